// Round 3
// baseline (1720.267 us; speedup 1.0000x reference)
//
#include <hip/hip_runtime.h>
#include <hip/hip_bf16.h>
#include <math.h>

// ---------------------------------------------------------------------------
// GPT decision-transformer forward on gfx950 — round 7.
// Round-7 change (single lever, A/B vs round-6): GEMM K-loop upgraded from
// 2-phase drain-0 (syncthreads per step = vmcnt(0) drain, exposes load
// latency every step) to a 3-buffer, 2-tiles-ahead counted-vmcnt pipeline
// (T3/T4-lite): per step issue stage(t+2), wait only vmcnt(SC) so tile t+1's
// loads keep ~2 K-steps of latency cover; raw s_barrier, never drain-0 in
// the main loop. LDS 24->36 KB (128-tile) = 4 blocks/CU.
// ---------------------------------------------------------------------------

typedef __hip_bfloat16 bf16;
typedef __attribute__((ext_vector_type(4))) short s4v;
typedef __attribute__((ext_vector_type(8))) short s8v;
typedef __attribute__((ext_vector_type(4))) float f4v;
typedef unsigned int u32;

#define DEV static __device__ __forceinline__
#define VMCNT_ASM(n) asm volatile("s_waitcnt vmcnt(" #n ")" ::: "memory")

constexpr int NBATCH = 2;
constexpr int NK   = 48;
constexpr int NNP  = 25;
constexpr int NC   = 768;
constexpr int NH   = 12;
constexpr int NL   = 6;
constexpr int NTOK = 29;
constexpr int NT   = NK * NTOK;    // 1392
constexpr int NM   = NBATCH * NT;  // 2784
constexpr int MPAD = 2816;         // 22 * 128

DEV float bs2f(short s) {
  unsigned u = ((unsigned)(unsigned short)s) << 16;
  float f; __builtin_memcpy(&f, &u, 4); return f;
}
DEV short f2bs(float f) {
  bf16 h = __float2bfloat16(f);
  short s; __builtin_memcpy(&s, &h, 2); return s;
}

// async global->LDS, 16 B/lane; LDS dest = wave-uniform base + lane*16
DEV void async16(const short* g, short* l) {
  __builtin_amdgcn_global_load_lds(
      (const __attribute__((address_space(1))) u32*)g,
      (__attribute__((address_space(3))) u32*)l, 16, 0, 0);
}

// ---------------------------------------------------------------------------
// Generic f32 (R,C) -> bf16 (C,R) transpose (for intW).
// ---------------------------------------------------------------------------
__global__ __launch_bounds__(256) void transpose_kernel(
    const float* __restrict__ src, bf16* __restrict__ dst, int R, int C)
{
  int c0 = blockIdx.x * 32, r0 = blockIdx.y * 32;
  __shared__ float tl[32][33];
  int rr = threadIdx.x >> 5, cc = threadIdx.x & 31;
#pragma unroll
  for (int p = 0; p < 4; p++)
    tl[rr + p * 8][cc] = src[(long)(r0 + rr + p * 8) * C + c0 + cc];
  __syncthreads();
#pragma unroll
  for (int p = 0; p < 4; p++)
    dst[(long)(c0 + rr + p * 8) * R + r0 + cc] = __float2bfloat16(tl[cc][rr + p * 8]);
}

// Per-layer (or all-layer) weight transpose+convert, 64x64 tiles.
// grid = 1728 * nlayers. multi=1: dst gets per-layer offset.
__global__ __launch_bounds__(256) void transpose_layer_kernel(
    const float* __restrict__ Wq, const float* __restrict__ Wk,
    const float* __restrict__ Wv, const float* __restrict__ Wo,
    const float* __restrict__ Wm1, const float* __restrict__ Wm2,
    bf16* __restrict__ WqkvT, bf16* __restrict__ WoT,
    bf16* __restrict__ Wm1T, bf16* __restrict__ Wm2T, int multi)
{
  int blk = blockIdx.x;
  int l = blk / 1728, t = blk - l * 1728;
  long so = (long)l * 768 * 768;
  long mo = (long)l * 768 * 3072;
  long dl = multi ? l : 0;
  const float* src; bf16* dst; int R, C, tile;
  if (t < 432) {
    int m = t / 144; tile = t - m * 144;
    src = (m == 0 ? Wq : (m == 1 ? Wk : Wv)) + so;
    dst = WqkvT + dl * (2304L * 768) + (long)m * 768 * 768; R = 768; C = 768;
  } else if (t < 576)  { src = Wo + so;  dst = WoT  + dl * (768L * 768);  tile = t - 432;  R = 768;  C = 768;  }
  else if (t < 1152)   { src = Wm1 + mo; dst = Wm1T + dl * (3072L * 768); tile = t - 576;  R = 768;  C = 3072; }
  else                 { src = Wm2 + mo; dst = Wm2T + dl * (768L * 3072); tile = t - 1152; R = 3072; C = 768;  }
  int ct = C / 64;
  int tr = tile / ct, tc = tile - tr * ct;
  int r0 = tr * 64, c0 = tc * 64;

  __shared__ short tl[64][66];
  int t4 = threadIdx.x & 15, rr = threadIdx.x >> 4;   // 16 lanes x 16 rows
#pragma unroll
  for (int p = 0; p < 4; p++) {
    int row = rr + p * 16;
    f4v v = *(const f4v*)(src + (long)(r0 + row) * C + c0 + t4 * 4);
    tl[t4 * 4 + 0][row] = f2bs(v.x);
    tl[t4 * 4 + 1][row] = f2bs(v.y);
    tl[t4 * 4 + 2][row] = f2bs(v.z);
    tl[t4 * 4 + 3][row] = f2bs(v.w);
  }
  __syncthreads();
#pragma unroll
  for (int p = 0; p < 4; p++) {
    int drow = rr + p * 16;     // dst row within tile = src col
    s4v w = *(const s4v*)&tl[drow][t4 * 4];
    *(s4v*)((short*)dst + (long)(c0 + drow) * R + r0 + t4 * 4) = w;
  }
}

// ---------------------------------------------------------------------------
// gather ie_in (96,1536) bf16 = [src_tab[i0] | dst_tab[i1]]
// ---------------------------------------------------------------------------
__global__ __launch_bounds__(256) void gather_ie_kernel(
    const int* __restrict__ intentions, const float* __restrict__ src_tab,
    const float* __restrict__ dst_tab, bf16* __restrict__ ie_in)
{
  int idx = blockIdx.x * 256 + threadIdx.x;
  if (idx >= 96 * 1536) return;
  int row = idx / 1536, col = idx - row * 1536;
  float v;
  if (col < 768) v = src_tab[intentions[row * 2 + 0] * 768 + col];
  else           v = dst_tab[intentions[row * 2 + 1] * 768 + col - 768];
  ie_in[idx] = __float2bfloat16(v);
}

// ---------------------------------------------------------------------------
// Embedding: X (B*T, C) f32. grid (96, 3); thread owns one channel c.
// ---------------------------------------------------------------------------
__global__ __launch_bounds__(256) void embed_kernel(
    const int* __restrict__ states, const int* __restrict__ actions,
    const float* __restrict__ rtgs, const int* __restrict__ timesteps,
    const float* __restrict__ pnp,
    const float* __restrict__ pos_emb, const float* __restrict__ gpe,
    const float* __restrict__ state_tab, const float* __restrict__ action_tab,
    const float* __restrict__ retW, const float* __restrict__ retb,
    const float* __restrict__ pnpW, const float* __restrict__ pnpb,
    const bf16* __restrict__ ieb, float* __restrict__ X)
{
  int bk = blockIdx.x;
  int b = bk / NK, ts = bk - b * NK;
  int c = blockIdx.y * 256 + threadIdx.x;

  float rtg = rtgs[bk];
  int tstep = timesteps[bk];
  int act   = actions[bk];

  long base = (long)(b * NT + ts * NTOK) * NC;
  float pos = gpe[(long)tstep * NC + c] + pos_emb[ts * NC + c];

  X[base + c] = rtg * retW[c] + retb[c] + pos;
  const int* sp = states + bk * NNP;
#pragma unroll
  for (int i = 0; i < NNP; i++)
    X[base + (1 + i) * NC + c] = state_tab[sp[i] * NC + c] + pos;
  X[base + 26 * NC + c] = action_tab[act * NC + c] + pos;
  float ap = pnpb[c];
  const float* pv = pnp + bk * NNP;
#pragma unroll
  for (int i = 0; i < NNP; i++) ap += pv[i] * pnpW[i * NC + c];
  X[base + 27 * NC + c] = ap + pos;
  X[base + 28 * NC + c] = __bfloat162float(ieb[bk * NC + c]) + pos;
}

// ---------------------------------------------------------------------------
// LayerNorm: X (f32) -> XN (bf16). One block per row.
// ---------------------------------------------------------------------------
__global__ __launch_bounds__(256) void ln_kernel(
    const float* __restrict__ X, bf16* __restrict__ XN,
    const float* __restrict__ g, const float* __restrict__ bt)
{
  int row = blockIdx.x, tid = threadIdx.x;
  const float* x = X + (long)row * NC;
  float v0 = x[tid], v1 = x[tid + 256], v2 = x[tid + 512];
  float s = v0 + v1 + v2;
#pragma unroll
  for (int o = 32; o > 0; o >>= 1) s += __shfl_down(s, o, 64);
  __shared__ float red[8];
  if ((tid & 63) == 0) red[tid >> 6] = s;
  __syncthreads();
  float mean = (red[0] + red[1] + red[2] + red[3]) * (1.0f / NC);
  float d0 = v0 - mean, d1 = v1 - mean, d2 = v2 - mean;
  float qq = d0 * d0 + d1 * d1 + d2 * d2;
#pragma unroll
  for (int o = 32; o > 0; o >>= 1) qq += __shfl_down(qq, o, 64);
  __syncthreads();
  if ((tid & 63) == 0) red[tid >> 6] = qq;
  __syncthreads();
  float var = (red[0] + red[1] + red[2] + red[3]) * (1.0f / NC);
  float rs = 1.0f / sqrtf(var + 1e-5f);
  bf16* xn = XN + (long)row * NC;
  xn[tid      ] = __float2bfloat16(d0 * rs * g[tid      ] + bt[tid      ]);
  xn[tid + 256] = __float2bfloat16(d1 * rs * g[tid + 256] + bt[tid + 256]);
  xn[tid + 512] = __float2bfloat16(d2 * rs * g[tid + 512] + bt[tid + 512]);
}

// ---------------------------------------------------------------------------
// Counted-vmcnt pipelined MFMA GEMM. A (rows,K) bf16 rm; WT (N,K) bf16 rm.
// 3 LDS buffers, 2 tiles prefetched ahead; per-step wait = vmcnt(SC)
// (SC = stage calls/thread/tile), so the next tile's loads are never waited
// on -- only the tile needed at the upcoming barrier. Raw s_barrier (no
// lgkmcnt/vmcnt drain). flags: bit0 GELU, bit1 resid += f32.
// ---------------------------------------------------------------------------
template<int BM, int BN>
__global__ __launch_bounds__(256) void gemm_kernel(
    const bf16* __restrict__ A, const bf16* __restrict__ WT,
    const float* __restrict__ b0, const float* __restrict__ b1,
    const float* __restrict__ b2, int Nsplit,
    bf16* __restrict__ outb, float* __restrict__ resid,
    int M, int N, int K, int flags)
{
  constexpr int IM  = BM / 64;   // MFMA row-subtiles per wave
  constexpr int JN  = BN / 16;   // MFMA col-subtiles per wave
  constexpr int ACH = BM / 64;   // A stage chunks per wave (16 rows each)
  constexpr int BCH = BN / 64;   // B stage chunks per wave
  constexpr int SC  = ACH + BCH; // stage calls per thread per K-tile
  static_assert(SC == 2 || SC == 3, "vmcnt literal dispatch");
  __shared__ __align__(1024) short As[3][BM * 32];
  __shared__ __align__(1024) short Bs[3][BN * 32];

  int tid = threadIdx.x, wave = tid >> 6, lane = tid & 63;
  int quad = lane >> 4, l16 = lane & 15;
  int m0 = blockIdx.y * BM, n0 = blockIdx.x * BN;
  int wm = wave * (BM / 4);
  int lr = lane >> 2, lc = (lane & 3) * 8;

  const short* Ag = (const short*)A + (long)m0 * K + lc;
  const short* Bg = (const short*)WT + (long)n0 * K + lc;

  const short* ag[ACH]; int alo[ACH];
#pragma unroll
  for (int c = 0; c < ACH; c++) {
    int rbase = wave * (16 * ACH) + c * 16;
    ag[c] = Ag + (long)(rbase + lr) * K;
    alo[c] = rbase * 32;
  }
  const short* bg[BCH]; int blo[BCH];
#pragma unroll
  for (int c = 0; c < BCH; c++) {
    int rbase = wave * (16 * BCH) + c * 16;
    bg[c] = Bg + (long)(rbase + lr) * K;
    blo[c] = rbase * 32;
  }

  f4v zero4 = {0.f, 0.f, 0.f, 0.f};
  f4v acc[IM][JN];
#pragma unroll
  for (int i = 0; i < IM; i++)
#pragma unroll
    for (int j = 0; j < JN; j++) acc[i][j] = zero4;

  int nk = K >> 5;

  // prologue: stage tiles 0 and 1; wait only for tile 0 (oldest SC ops)
#pragma unroll
  for (int c = 0; c < ACH; c++) async16(ag[c], &As[0][alo[c]]);
#pragma unroll
  for (int c = 0; c < BCH; c++) async16(bg[c], &Bs[0][blo[c]]);
  if (nk > 1) {
    int ko = 32;
#pragma unroll
    for (int c = 0; c < ACH; c++) async16(ag[c] + ko, &As[1][alo[c]]);
#pragma unroll
    for (int c = 0; c < BCH; c++) async16(bg[c] + ko, &Bs[1][blo[c]]);
    if constexpr (SC == 2) VMCNT_ASM(2); else VMCNT_ASM(3);
  } else {
    VMCNT_ASM(0);
  }
  __builtin_amdgcn_s_barrier();
  __builtin_amdgcn_sched_barrier(0);

  for (int kt = 0; kt < nk; kt++) {
    int cur = kt % 3;
    if (kt + 2 < nk) {
      int nb = (kt + 2) % 3;
      int ko = (kt + 2) << 5;
#pragma unroll
      for (int c = 0; c < ACH; c++) async16(ag[c] + ko, &As[nb][alo[c]]);
#pragma unroll
      for (int c = 0; c < BCH; c++) async16(bg[c] + ko, &Bs[nb][blo[c]]);
    }
    s8v af[IM], bf8[JN];
#pragma unroll
    for (int i = 0; i < IM; i++) {
      const short* p = &As[cur][(wm + i * 16 + l16) * 32 + quad * 8];
      af[i].lo = *(const s4v*)p; af[i].hi = *(const s4v*)(p + 4);
    }
#pragma unroll
    for (int j = 0; j < JN; j++) {
      const short* p = &Bs[cur][(j * 16 + l16) * 32 + quad * 8];
      bf8[j].lo = *(const s4v*)p; bf8[j].hi = *(const s4v*)(p + 4);
    }
#pragma unroll
    for (int i = 0; i < IM; i++)
#pragma unroll
      for (int j = 0; j < JN; j++)
        acc[i][j] = __builtin_amdgcn_mfma_f32_16x16x32_bf16(af[i], bf8[j], acc[i][j], 0, 0, 0);
    if (kt + 1 < nk) {
      // wait for tile kt+1 (oldest SC in flight); tile kt+2 stays in flight
      if (kt + 2 < nk) { if constexpr (SC == 2) VMCNT_ASM(2); else VMCNT_ASM(3); }
      else             { VMCNT_ASM(0); }
      __builtin_amdgcn_s_barrier();
      __builtin_amdgcn_sched_barrier(0);
    }
  }

  // epilogue: C/D layout col=lane&15, row=quad*4+reg
#pragma unroll
  for (int i = 0; i < IM; i++) {
    int rbase = m0 + wm + i * 16 + quad * 4;
#pragma unroll
    for (int j = 0; j < JN; j++) {
      int bc = n0 + j * 16;
      int wsel = bc / Nsplit;
      const float* bp = wsel == 0 ? b0 : (wsel == 1 ? b1 : b2);
      float bv = bp[bc - wsel * Nsplit + l16];
      int col = bc + l16;
#pragma unroll
      for (int r = 0; r < 4; r++) {
        int row = rbase + r;
        if (row < M) {
          float v = acc[i][j][r] + bv;
          if (flags & 1) v = 0.5f * v * (1.0f + erff(v * 0.70710678118654752f));
          if (flags & 2) resid[(long)row * N + col] += v;
          else outb[(long)row * N + col] = __float2bfloat16(v);
        }
      }
    }
  }
}

// ---------------------------------------------------------------------------
// Flash-style causal attention, in-register online softmax.
// QKV packed (MPAD,2304). Output Yg bf16. One head-tile (64 q-rows) per
// block; S-row (q-row) is owned by one 16-lane group of one wave, so max/sum
// reduce via 4x __shfl_xor; running m/l live in registers. 3 barriers/tile.
// ---------------------------------------------------------------------------
constexpr int ASTR = 72;

__global__ __launch_bounds__(256) void attn_kernel(
    const bf16* __restrict__ QKV, bf16* __restrict__ Yg)
{
  int qt = blockIdx.x, h = blockIdx.y, b = blockIdx.z;
  int q0 = qt * 64;
  int tid = threadIdx.x, wave = tid >> 6, lane = tid & 63, quad = lane >> 4, l16 = lane & 15;

  __shared__ short Qs[64 * ASTR];
  __shared__ short Ks[64 * ASTR];
  __shared__ short Vt[64 * ASTR];
  __shared__ short Ps[64 * ASTR];

  int r = tid >> 2, c16 = (tid & 3) * 16;
  const short* src = (const short*)QKV;
  s8v zz = {0,0,0,0,0,0,0,0};

  // Q -> LDS
  s8v qv0 = zz, qv1 = zz;
  if (q0 + r < NT) {
    const s8v* p = (const s8v*)(src + (long)(b * NT + q0 + r) * 2304 + h * 64 + c16);
    qv0 = p[0]; qv1 = p[1];
  }
  {
    short* qp = &Qs[r * ASTR + c16];
    *(s4v*)(qp    ) = qv0.lo; *(s4v*)(qp + 4) = qv0.hi;
    *(s4v*)(qp + 8) = qv1.lo; *(s4v*)(qp + 12) = qv1.hi;
  }

  f4v zero4 = {0.f, 0.f, 0.f, 0.f};
  f4v Of[4];
#pragma unroll
  for (int j = 0; j < 4; j++) Of[j] = zero4;
  float m_r[4], l_r[4];
#pragma unroll
  for (int rg = 0; rg < 4; rg++) { m_r[rg] = -1e30f; l_r[rg] = 0.f; }

  int kend = q0 + 63; if (kend > NT - 1) kend = NT - 1;

  // preload K/V tile 0
  s8v kv0 = zz, kv1 = zz, vv0 = zz, vv1 = zz;
  if (r < NT) {
    const s8v* pk = (const s8v*)(src + (long)(b * NT + r) * 2304 + 768 + h * 64 + c16);
    kv0 = pk[0]; kv1 = pk[1];
    const s8v* pvv = (const s8v*)(src + (long)(b * NT + r) * 2304 + 1536 + h * 64 + c16);
    vv0 = pvv[0]; vv1 = pvv[1];
  }

  for (int k0 = 0; k0 <= kend; k0 += 64) {
    __syncthreads();   // prev-tile PV reads done (iter0: also spaces Qs write)
    {
      short* kp = &Ks[r * ASTR + c16];
      *(s4v*)(kp    ) = kv0.lo; *(s4v*)(kp + 4) = kv0.hi;
      *(s4v*)(kp + 8) = kv1.lo; *(s4v*)(kp + 12) = kv1.hi;
      short* vt = &Vt[c16 * ASTR + r];
      vt[ 0 * ASTR] = vv0.s0; vt[ 1 * ASTR] = vv0.s1; vt[ 2 * ASTR] = vv0.s2; vt[ 3 * ASTR] = vv0.s3;
      vt[ 4 * ASTR] = vv0.s4; vt[ 5 * ASTR] = vv0.s5; vt[ 6 * ASTR] = vv0.s6; vt[ 7 * ASTR] = vv0.s7;
      vt[ 8 * ASTR] = vv1.s0; vt[ 9 * ASTR] = vv1.s1; vt[10 * ASTR] = vv1.s2; vt[11 * ASTR] = vv1.s3;
      vt[12 * ASTR] = vv1.s4; vt[13 * ASTR] = vv1.s5; vt[14 * ASTR] = vv1.s6; vt[15 * ASTR] = vv1.s7;
    }
    __syncthreads();   // K/V tile ready

    // prefetch next K/V tile under compute
    int k1 = k0 + 64;
    s8v nk0 = zz, nk1 = zz, nv0 = zz, nv1 = zz;
    if (k1 <= kend && k1 + r < NT) {
      const s8v* pk = (const s8v*)(src + (long)(b * NT + k1 + r) * 2304 + 768 + h * 64 + c16);
      nk0 = pk[0]; nk1 = pk[1];
      const s8v* pvv = (const s8v*)(src + (long)(b * NT + k1 + r) * 2304 + 1536 + h * 64 + c16);
      nv0 = pvv[0]; nv1 = pvv[1];
    }

    // QK^T: sa[j][rg] = S[wave*16+quad*4+rg][j*16+l16]
    f4v sa[4];
#pragma unroll
    for (int j = 0; j < 4; j++) sa[j] = zero4;
#pragma unroll
    for (int ks = 0; ks < 2; ks++) {
      const short* pa = &Qs[(wave * 16 + l16) * ASTR + ks * 32 + quad * 8];
      s8v aq; aq.lo = *(const s4v*)pa; aq.hi = *(const s4v*)(pa + 4);
#pragma unroll
      for (int j = 0; j < 4; j++) {
        const short* pb = &Ks[(j * 16 + l16) * ASTR + ks * 32 + quad * 8];
        s8v bk8; bk8.lo = *(const s4v*)pb; bk8.hi = *(const s4v*)(pb + 4);
        sa[j] = __builtin_amdgcn_mfma_f32_16x16x32_bf16(aq, bk8, sa[j], 0, 0, 0);
      }
    }

    // scale + causal mask in-register
#pragma unroll
    for (int j = 0; j < 4; j++) {
#pragma unroll
      for (int rg = 0; rg < 4; rg++) {
        int gq = q0 + wave * 16 + quad * 4 + rg;
        int gk = k0 + j * 16 + l16;
        sa[j][rg] = (gk <= gq && gq < NT) ? sa[j][rg] * 0.125f : -1e30f;
      }
    }

    // in-register online softmax per row rg (row spread over l16 x j)
#pragma unroll
    for (int rg = 0; rg < 4; rg++) {
      float mx = fmaxf(fmaxf(sa[0][rg], sa[1][rg]), fmaxf(sa[2][rg], sa[3][rg]));
      mx = fmaxf(mx, __shfl_xor(mx, 1));
      mx = fmaxf(mx, __shfl_xor(mx, 2));
      mx = fmaxf(mx, __shfl_xor(mx, 4));
      mx = fmaxf(mx, __shfl_xor(mx, 8));
      float mn = fmaxf(m_r[rg], mx);
      float al = __expf(m_r[rg] - mn);
      m_r[rg] = mn;
      float ps = 0.f;
#pragma unroll
      for (int j = 0; j < 4; j++) {
        float e = __expf(sa[j][rg] - mn);
        sa[j][rg] = e;
        ps += e;
      }
      ps += __shfl_xor(ps, 1);
      ps += __shfl_xor(ps, 2);
      ps += __shfl_xor(ps, 4);
      ps += __shfl_xor(ps, 8);
      l_r[rg] = l_r[rg] * al + ps;
#pragma unroll
      for (int j = 0; j < 4; j++) Of[j][rg] *= al;
    }

    // P -> LDS (bf16) for the PV A-operand
#pragma unroll
    for (int j = 0; j < 4; j++)
#pragma unroll
      for (int rg = 0; rg < 4; rg++)
        Ps[(wave * 16 + quad * 4 + rg) * ASTR + j * 16 + l16] = f2bs(sa[j][rg]);
    __syncthreads();   // Ps ready

    // PV
#pragma unroll
    for (int ks = 0; ks < 2; ks++) {
      const short* pa = &Ps[(wave * 16 + l16) * ASTR + ks * 32 + quad * 8];
      s8v ap8; ap8.lo = *(const s4v*)pa; ap8.hi = *(const s4v*)(pa + 4);
#pragma unroll
      for (int j = 0; j < 4; j++) {
        const short* pb = &Vt[(j * 16 + l16) * ASTR + ks * 32 + quad * 8];
        s8v vp8; vp8.lo = *(const s4v*)pb; vp8.hi = *(const s4v*)(pb + 4);
        Of[j] = __builtin_amdgcn_mfma_f32_16x16x32_bf16(ap8, vp8, Of[j], 0, 0, 0);
      }
    }

    kv0 = nk0; kv1 = nk1; vv0 = nv0; vv1 = nv1;
  }

  // epilogue
#pragma unroll
  for (int rg = 0; rg < 4; rg++) {
    int rloc = wave * 16 + quad * 4 + rg;
    int gq = q0 + rloc;
    if (gq < NT) {
      float inv = 1.0f / l_r[rg];
#pragma unroll
      for (int j = 0; j < 4; j++) {
        float ov = Of[j][rg] * inv;
        Yg[(long)(b * NT + gq) * NC + h * 64 + j * 16 + l16] = __float2bfloat16(ov);
      }
    }
  }
}

// ---------------------------------------------------------------------------
// Heads
// ---------------------------------------------------------------------------
__global__ __launch_bounds__(256) void head_logits_kernel(
    const bf16* __restrict__ XN, const float* __restrict__ Whs,
    const float* __restrict__ bhs, float* __restrict__ out)
{
  int idx = blockIdx.x * 256 + threadIdx.x;
  if (idx >= NM * 10) return;
  int row = idx / 10, n = idx - row * 10;
  const short* x = (const short*)XN + (long)row * NC;
  float a0 = bhs[n], a1 = 0.f, a2 = 0.f, a3 = 0.f;
  for (int k = 0; k < NC; k += 4) {
    a0 += bs2f(x[k    ]) * Whs[(k    ) * 10 + n];
    a1 += bs2f(x[k + 1]) * Whs[(k + 1) * 10 + n];
    a2 += bs2f(x[k + 2]) * Whs[(k + 2) * 10 + n];
    a3 += bs2f(x[k + 3]) * Whs[(k + 3) * 10 + n];
  }
  out[idx] = a0 + a1 + a2 + a3;
}

__global__ __launch_bounds__(128) void head_small_kernel(
    const bf16* __restrict__ XN,
    const float* __restrict__ Wha, const float* __restrict__ bha,
    const float* __restrict__ Whr, const float* __restrict__ bhr,
    const float* __restrict__ Whi, const float* __restrict__ bhi,
    float* __restrict__ outA, float* __restrict__ outR,
    float* __restrict__ outS, float* __restrict__ outD)
{
  int blk = blockIdx.x;
  int b = blk / NK, ts = blk - b * NK;
  int tid = threadIdx.x;
  if (tid >= 93) return;
  const short* xs = (const short*)XN;
  if (tid < 40) {
    long row = (long)(b * NT + ts * NTOK + 26) * NC;
    float a0 = bha[tid], a1 = 0.f, a2 = 0.f, a3 = 0.f;
    for (int k = 0; k < NC; k += 4) {
      a0 += bs2f(xs[row + k    ]) * Wha[(k    ) * 40 + tid];
      a1 += bs2f(xs[row + k + 1]) * Wha[(k + 1) * 40 + tid];
      a2 += bs2f(xs[row + k + 2]) * Wha[(k + 2) * 40 + tid];
      a3 += bs2f(xs[row + k + 3]) * Wha[(k + 3) * 40 + tid];
    }
    outA[blk * 40 + tid] = a0 + a1 + a2 + a3;
  } else if (tid == 40) {
    long row = (long)(b * NT + ts * NTOK) * NC;
    float a0 = bhr[0], a1 = 0.f, a2 = 0.f, a3 = 0.f;
    for (int k = 0; k < NC; k += 4) {
      a0 += bs2f(xs[row + k    ]) * Whr[k    ];
      a1 += bs2f(xs[row + k + 1]) * Whr[k + 1];
      a2 += bs2f(xs[row + k + 2]) * Whr[k + 2];
      a3 += bs2f(xs[row + k + 3]) * Whr[k + 3];
    }
    outR[blk] = a0 + a1 + a2 + a3;
  } else {
    int n = tid - 41;
    long row = (long)(b * NT + ts * NTOK + 28) * NC;
    float a0 = bhi[n], a1 = 0.f, a2 = 0.f, a3 = 0.f;
    for (int k = 0; k < NC; k += 4) {
      a0 += bs2f(xs[row + k    ]) * Whi[(k    ) * 52 + n];
      a1 += bs2f(xs[row + k + 1]) * Whi[(k + 1) * 52 + n];
      a2 += bs2f(xs[row + k + 2]) * Whi[(k + 2) * 52 + n];
      a3 += bs2f(xs[row + k + 3]) * Whi[(k + 3) * 52 + n];
    }
    if (n < 26) outS[blk * 26 + n] = a0 + a1 + a2 + a3;
    else        outD[blk * 26 + (n - 26)] = a0 + a1 + a2 + a3;
  }
}

// ---------------------------------------------------------------------------
extern "C" void kernel_launch(void* const* d_in, const int* in_sizes, int n_in,
                              void* d_out, int out_size, void* d_ws, size_t ws_size,
                              hipStream_t stream)
{
  (void)in_sizes; (void)n_in; (void)out_size;

  const int*   states     = (const int*)  d_in[0];
  const int*   actions    = (const int*)  d_in[1];
  const float* rtgs       = (const float*)d_in[2];
  const int*   timesteps  = (const int*)  d_in[3];
  const float* pnp        = (const float*)d_in[4];
  const int*   intentions = (const int*)  d_in[5];
  const float* pos_emb    = (const float*)d_in[6];
  const float* gpe        = (const float*)d_in[7];
  const float* state_tab  = (const float*)d_in[8];
  const float* action_tab = (const float*)d_in[9];
  const float* retW  = (const float*)d_in[10];
  const float* retb  = (const float*)d_in[11];
  const float* pnpW  = (const float*)d_in[12];
  const float* pnpb  = (const float*)d_in[13];
  const float* src_tab = (const float*)d_in[14];
  const float* dst_tab = (const float*)d_in[15];
  const float* intW  = (const float*)d_in[16];
  const float* intb  = (const float*)d_in[17];
  const float* ln1g  = (const float*)d_in[18];
  const float* ln1b  = (const float*)d_in[19];
  const float* ln2g  = (const float*)d_in[20];
  const float* ln2b  = (const float*)d_in[21];
  const float* Wq = (const float*)d_in[22];
  const float* bq = (const float*)d_in[23];
  const float* Wk = (const float*)d_in[24];
  const float* bk = (const float*)d_in[25];
  const float* Wv = (const float*)d_in[26];
  const float* bv = (const float*)d_in[27];
  const float* Wo = (const float*)d_in[28];
  const float* bo = (const float*)d_in[29];
  const float* Wm1 = (const float*)d_in[30];
  const float* bm1 = (const float*)d_in[31];
  const float* Wm2 = (const float*)d_in[32];
  const float* bm2 = (const float*)d_in[33];
  const float* lnfg = (const float*)d_in[34];
  const float* lnfb = (const float*)d_in[35];
  const float* Whs = (const float*)d_in[36];
  const float* bhs = (const float*)d_in[37];
  const float* Wha = (const float*)d_in[38];
  const float* bha = (const float*)d_in[39];
  const float* Whr = (const float*)d_in[40];
  const float* bhr = (const float*)d_in[41];
  const float* Whi = (const float*)d_in[42];
  const float* bhi = (const float*)d_in[43];

  // ws: [0, 30,277,632) activations: X f32 | XN bf16 | QKVb bf16 | Yb bf16
  // then weight region. big path: all-6-layer bf16 weights (84,934,656 B)
  // + int-embed scratch; fallback: single-layer weights (14,155,776 B) with
  // int-embed scratch overlapped (consumed before first layer transpose).
  char* wsb = (char*)d_ws;
  float* X   = (float*)(wsb);
  bf16* XN   = (bf16*)(wsb + 8650752);
  bf16* QKVb = (bf16*)(wsb + 12976128);
  bf16* Yb   = (bf16*)(wsb + 25952256);
  bf16* H1   = QKVb;                          // aliases QKVb|Yb
  bf16* WTbase = (bf16*)(wsb + 30277632);

  const size_t NEED_BIG = 30277632UL + 84934656UL + 2949120UL;  // 118,161,408
  bool big = ws_size >= NEED_BIG;

  long sQKV = 2304L * 768, sO = 768L * 768, sM1 = 3072L * 768, sM2 = 768L * 3072;
  bf16 *WqkvT, *WoT, *Wm1T, *Wm2T, *intWT;
  if (big) {
    WqkvT = WTbase;                 // 6 x sQKV
    WoT   = WqkvT + 6 * sQKV;       // 6 x sO
    Wm1T  = WoT   + 6 * sO;         // 6 x sM1
    Wm2T  = Wm1T  + 6 * sM1;        // 6 x sM2
    intWT = Wm2T  + 6 * sM2;
  } else {
    WqkvT = WTbase;
    WoT   = WqkvT + sQKV;
    Wm1T  = WoT + sO;
    Wm2T  = Wm1T + sM1;
    intWT = WTbase;                 // overlapped; consumed pre-transpose
  }
  bf16* ie_in = intWT + 768L * 1536;   // (128,1536)
  bf16* ieb   = ie_in + 128L * 1536;   // (128,768)

  float* out0 = (float*)d_out;
  float* out1 = out0 + 27840;
  float* out2 = out1 + 3840;
  float* out3 = out2 + 96;
  float* out4 = out3 + 2496;

  // --- embeddings ---
  transpose_kernel<<<dim3(24, 48), 256, 0, stream>>>(intW, intWT, 1536, 768);
  gather_ie_kernel<<<(96 * 1536 + 255) / 256, 256, 0, stream>>>(intentions, src_tab, dst_tab, ie_in);
  gemm_kernel<64, 64><<<dim3(12, 2), 256, 0, stream>>>(ie_in, intWT, intb, intb, intb, 768,
      ieb, nullptr, 96, 768, 1536, 0);
  embed_kernel<<<dim3(96, 3), 256, 0, stream>>>(
      states, actions, rtgs, timesteps, pnp, pos_emb, gpe, state_tab, action_tab,
      retW, retb, pnpW, pnpb, ieb, X);

  if (big)
    transpose_layer_kernel<<<1728 * NL, 256, 0, stream>>>(
        Wq, Wk, Wv, Wo, Wm1, Wm2, WqkvT, WoT, Wm1T, Wm2T, 1);

  // --- transformer stack ---
  for (int l = 0; l < NL; l++) {
    const long wofs = (long)l * NC * NC;
    const long mofs = (long)l * NC * 4 * NC;
    if (!big)
      transpose_layer_kernel<<<1728, 256, 0, stream>>>(
          Wq + wofs, Wk + wofs, Wv + wofs, Wo + wofs, Wm1 + mofs, Wm2 + mofs,
          WqkvT, WoT, Wm1T, Wm2T, 0);
    bf16* wqkv = big ? WqkvT + l * sQKV : WqkvT;
    bf16* wo   = big ? WoT   + l * sO   : WoT;
    bf16* wm1  = big ? Wm1T  + l * sM1  : Wm1T;
    bf16* wm2  = big ? Wm2T  + l * sM2  : Wm2T;

    ln_kernel<<<NM, 256, 0, stream>>>(X, XN, ln1g + l * NC, ln1b + l * NC);
    gemm_kernel<128, 64><<<dim3(36, 22), 256, 0, stream>>>(XN, wqkv,
        bq + l * NC, bk + l * NC, bv + l * NC, 768, QKVb, nullptr, NM, 2304, NC, 0);
    attn_kernel<<<dim3(22, NH, NBATCH), 256, 0, stream>>>(QKVb, Yb);
    gemm_kernel<64, 64><<<dim3(12, 44), 256, 0, stream>>>(Yb, wo,
        bo + l * NC, bo + l * NC, bo + l * NC, 768, nullptr, X, NM, 768, NC, 2);
    ln_kernel<<<NM, 256, 0, stream>>>(X, XN, ln2g + l * NC, ln2b + l * NC);
    gemm_kernel<128, 64><<<dim3(48, 22), 256, 0, stream>>>(XN, wm1,
        bm1 + l * 4 * NC, bm1 + l * 4 * NC, bm1 + l * 4 * NC, 4 * NC, H1, nullptr,
        NM, 3072, NC, 1);
    gemm_kernel<64, 64><<<dim3(12, 44), 256, 0, stream>>>(H1, wm2,
        bm2 + l * NC, bm2 + l * NC, bm2 + l * NC, 768, nullptr, X, NM, 768, 4 * NC, 2);
  }
  ln_kernel<<<NM, 256, 0, stream>>>(X, XN, lnfg, lnfb);
  head_logits_kernel<<<(NM * 10 + 255) / 256, 256, 0, stream>>>(XN, Whs, bhs, out0);
  head_small_kernel<<<NBATCH * NK, 128, 0, stream>>>(XN, Wha, bha, Whr, bhr, Whi, bhi,
      out1, out2, out3, out4);
}

// Round 4
// 1589.038 us; speedup vs baseline: 1.0826x; 1.0826x over previous
//
#include <hip/hip_runtime.h>
#include <hip/hip_bf16.h>
#include <math.h>

// ---------------------------------------------------------------------------
// GPT decision-transformer forward on gfx950 — round 8.
// Round-8 changes: (1) GEMM reverted to round-6 2-buffer schedule (counted
// vmcnt 3-buf regressed -96us via occupancy loss). (2) transpose_layer uses
// 128x64 tiles: dst rows written as full 256B contiguous segments (was 128B)
// to fix DRAM burst locality (2.2 TB/s -> target ~3.5). (3) ln_kernel
// wave-per-row (4 rows/block, no LDS/barriers, 696 blocks). (4) two head
// kernels merged into one dispatch.
// ---------------------------------------------------------------------------

typedef __hip_bfloat16 bf16;
typedef __attribute__((ext_vector_type(4))) short s4v;
typedef __attribute__((ext_vector_type(8))) short s8v;
typedef __attribute__((ext_vector_type(4))) float f4v;
typedef unsigned int u32;

#define DEV static __device__ __forceinline__

constexpr int NBATCH = 2;
constexpr int NK   = 48;
constexpr int NNP  = 25;
constexpr int NC   = 768;
constexpr int NH   = 12;
constexpr int NL   = 6;
constexpr int NTOK = 29;
constexpr int NT   = NK * NTOK;    // 1392
constexpr int NM   = NBATCH * NT;  // 2784
constexpr int MPAD = 2816;         // 22 * 128

DEV float bs2f(short s) {
  unsigned u = ((unsigned)(unsigned short)s) << 16;
  float f; __builtin_memcpy(&f, &u, 4); return f;
}
DEV short f2bs(float f) {
  bf16 h = __float2bfloat16(f);
  short s; __builtin_memcpy(&s, &h, 2); return s;
}

// async global->LDS, 16 B/lane; LDS dest = wave-uniform base + lane*16
DEV void async16(const short* g, short* l) {
  __builtin_amdgcn_global_load_lds(
      (const __attribute__((address_space(1))) u32*)g,
      (__attribute__((address_space(3))) u32*)l, 16, 0, 0);
}

// ---------------------------------------------------------------------------
// Generic f32 (R,C) -> bf16 (C,R) transpose (for intW).
// ---------------------------------------------------------------------------
__global__ __launch_bounds__(256) void transpose_kernel(
    const float* __restrict__ src, bf16* __restrict__ dst, int R, int C)
{
  int c0 = blockIdx.x * 32, r0 = blockIdx.y * 32;
  __shared__ float tl[32][33];
  int rr = threadIdx.x >> 5, cc = threadIdx.x & 31;
#pragma unroll
  for (int p = 0; p < 4; p++)
    tl[rr + p * 8][cc] = src[(long)(r0 + rr + p * 8) * C + c0 + cc];
  __syncthreads();
#pragma unroll
  for (int p = 0; p < 4; p++)
    dst[(long)(c0 + rr + p * 8) * R + r0 + cc] = __float2bfloat16(tl[cc][rr + p * 8]);
}

// Per-layer (or all-layer) weight transpose+convert, 128x64 tiles.
// Reads 256B/src-row; writes full dst rows (128 src-rows = 256B contiguous).
// grid = 864 * nlayers. multi=1: dst gets per-layer offset.
__global__ __launch_bounds__(256) void transpose_layer_kernel(
    const float* __restrict__ Wq, const float* __restrict__ Wk,
    const float* __restrict__ Wv, const float* __restrict__ Wo,
    const float* __restrict__ Wm1, const float* __restrict__ Wm2,
    bf16* __restrict__ WqkvT, bf16* __restrict__ WoT,
    bf16* __restrict__ Wm1T, bf16* __restrict__ Wm2T, int multi)
{
  int blk = blockIdx.x;
  int l = blk / 864, t = blk - l * 864;
  long so = (long)l * 768 * 768;
  long mo = (long)l * 768 * 3072;
  long dl = multi ? l : 0;
  const float* src; bf16* dst; int R, C, tile;
  if (t < 216) {
    int m = t / 72; tile = t - m * 72;
    src = (m == 0 ? Wq : (m == 1 ? Wk : Wv)) + so;
    dst = WqkvT + dl * (2304L * 768) + (long)m * 768 * 768; R = 768; C = 768;
  } else if (t < 288)  { src = Wo + so;  dst = WoT  + dl * (768L * 768);  tile = t - 216; R = 768;  C = 768;  }
  else if (t < 576)    { src = Wm1 + mo; dst = Wm1T + dl * (3072L * 768); tile = t - 288; R = 768;  C = 3072; }
  else                 { src = Wm2 + mo; dst = Wm2T + dl * (768L * 3072); tile = t - 576; R = 3072; C = 768;  }
  int ct = C / 64;
  int tr = tile / ct, tc = tile - tr * ct;
  int r0 = tr * 128, c0 = tc * 64;

  __shared__ short tl[128][66];
  int cg = threadIdx.x & 15, rg = threadIdx.x >> 4;   // 16 col-chunks x 16 row-groups
#pragma unroll
  for (int p = 0; p < 8; p++) {
    int row = rg + p * 16;
    f4v v = *(const f4v*)(src + (long)(r0 + row) * C + c0 + cg * 4);
    tl[row][cg * 4 + 0] = f2bs(v.x);
    tl[row][cg * 4 + 1] = f2bs(v.y);
    tl[row][cg * 4 + 2] = f2bs(v.z);
    tl[row][cg * 4 + 3] = f2bs(v.w);
  }
  __syncthreads();
#pragma unroll
  for (int p = 0; p < 4; p++) {
    int d = rg + p * 16;          // dst row = src col (0..63)
    const short* base = &tl[cg * 8][d];
    s8v w;
    w.s0 = base[0 * 66]; w.s1 = base[1 * 66]; w.s2 = base[2 * 66]; w.s3 = base[3 * 66];
    w.s4 = base[4 * 66]; w.s5 = base[5 * 66]; w.s6 = base[6 * 66]; w.s7 = base[7 * 66];
    *(s8v*)((short*)dst + (long)(c0 + d) * R + r0 + cg * 8) = w;
  }
}

// ---------------------------------------------------------------------------
// gather ie_in (96,1536) bf16 = [src_tab[i0] | dst_tab[i1]]
// ---------------------------------------------------------------------------
__global__ __launch_bounds__(256) void gather_ie_kernel(
    const int* __restrict__ intentions, const float* __restrict__ src_tab,
    const float* __restrict__ dst_tab, bf16* __restrict__ ie_in)
{
  int idx = blockIdx.x * 256 + threadIdx.x;
  if (idx >= 96 * 1536) return;
  int row = idx / 1536, col = idx - row * 1536;
  float v;
  if (col < 768) v = src_tab[intentions[row * 2 + 0] * 768 + col];
  else           v = dst_tab[intentions[row * 2 + 1] * 768 + col - 768];
  ie_in[idx] = __float2bfloat16(v);
}

// ---------------------------------------------------------------------------
// Embedding: X (B*T, C) f32. grid (96, 3); thread owns one channel c.
// ---------------------------------------------------------------------------
__global__ __launch_bounds__(256) void embed_kernel(
    const int* __restrict__ states, const int* __restrict__ actions,
    const float* __restrict__ rtgs, const int* __restrict__ timesteps,
    const float* __restrict__ pnp,
    const float* __restrict__ pos_emb, const float* __restrict__ gpe,
    const float* __restrict__ state_tab, const float* __restrict__ action_tab,
    const float* __restrict__ retW, const float* __restrict__ retb,
    const float* __restrict__ pnpW, const float* __restrict__ pnpb,
    const bf16* __restrict__ ieb, float* __restrict__ X)
{
  int bk = blockIdx.x;
  int b = bk / NK, ts = bk - b * NK;
  int c = blockIdx.y * 256 + threadIdx.x;

  float rtg = rtgs[bk];
  int tstep = timesteps[bk];
  int act   = actions[bk];

  long base = (long)(b * NT + ts * NTOK) * NC;
  float pos = gpe[(long)tstep * NC + c] + pos_emb[ts * NC + c];

  X[base + c] = rtg * retW[c] + retb[c] + pos;
  const int* sp = states + bk * NNP;
#pragma unroll
  for (int i = 0; i < NNP; i++)
    X[base + (1 + i) * NC + c] = state_tab[sp[i] * NC + c] + pos;
  X[base + 26 * NC + c] = action_tab[act * NC + c] + pos;
  float ap = pnpb[c];
  const float* pv = pnp + bk * NNP;
#pragma unroll
  for (int i = 0; i < NNP; i++) ap += pv[i] * pnpW[i * NC + c];
  X[base + 27 * NC + c] = ap + pos;
  X[base + 28 * NC + c] = __bfloat162float(ieb[bk * NC + c]) + pos;
}

// ---------------------------------------------------------------------------
// LayerNorm: X (f32) -> XN (bf16). Wave per row, 4 rows per block.
// No LDS, no barriers; butterfly shfl_xor reduce over 64 lanes.
// ---------------------------------------------------------------------------
__global__ __launch_bounds__(256) void ln_kernel(
    const float* __restrict__ X, bf16* __restrict__ XN,
    const float* __restrict__ g, const float* __restrict__ bt)
{
  int row = blockIdx.x * 4 + (threadIdx.x >> 6);
  int lane = threadIdx.x & 63;
  const float* x = X + (long)row * NC;
  f4v v0 = *(const f4v*)(x + lane * 4);
  f4v v1 = *(const f4v*)(x + 256 + lane * 4);
  f4v v2 = *(const f4v*)(x + 512 + lane * 4);
  float s = v0.x + v0.y + v0.z + v0.w + v1.x + v1.y + v1.z + v1.w
          + v2.x + v2.y + v2.z + v2.w;
#pragma unroll
  for (int o = 32; o > 0; o >>= 1) s += __shfl_xor(s, o);
  float mean = s * (1.0f / NC);
  f4v d0, d1, d2;
  d0.x = v0.x - mean; d0.y = v0.y - mean; d0.z = v0.z - mean; d0.w = v0.w - mean;
  d1.x = v1.x - mean; d1.y = v1.y - mean; d1.z = v1.z - mean; d1.w = v1.w - mean;
  d2.x = v2.x - mean; d2.y = v2.y - mean; d2.z = v2.z - mean; d2.w = v2.w - mean;
  float qq = d0.x*d0.x + d0.y*d0.y + d0.z*d0.z + d0.w*d0.w
           + d1.x*d1.x + d1.y*d1.y + d1.z*d1.z + d1.w*d1.w
           + d2.x*d2.x + d2.y*d2.y + d2.z*d2.z + d2.w*d2.w;
#pragma unroll
  for (int o = 32; o > 0; o >>= 1) qq += __shfl_xor(qq, o);
  float var = qq * (1.0f / NC);
  float rs = 1.0f / sqrtf(var + 1e-5f);
  short* xn = (short*)XN + (long)row * NC;
  f4v g0 = *(const f4v*)(g + lane * 4);
  f4v g1 = *(const f4v*)(g + 256 + lane * 4);
  f4v g2 = *(const f4v*)(g + 512 + lane * 4);
  f4v b0 = *(const f4v*)(bt + lane * 4);
  f4v b1 = *(const f4v*)(bt + 256 + lane * 4);
  f4v b2 = *(const f4v*)(bt + 512 + lane * 4);
  s4v w0, w1, w2;
  w0.x = f2bs(d0.x * rs * g0.x + b0.x); w0.y = f2bs(d0.y * rs * g0.y + b0.y);
  w0.z = f2bs(d0.z * rs * g0.z + b0.z); w0.w = f2bs(d0.w * rs * g0.w + b0.w);
  w1.x = f2bs(d1.x * rs * g1.x + b1.x); w1.y = f2bs(d1.y * rs * g1.y + b1.y);
  w1.z = f2bs(d1.z * rs * g1.z + b1.z); w1.w = f2bs(d1.w * rs * g1.w + b1.w);
  w2.x = f2bs(d2.x * rs * g2.x + b2.x); w2.y = f2bs(d2.y * rs * g2.y + b2.y);
  w2.z = f2bs(d2.z * rs * g2.z + b2.z); w2.w = f2bs(d2.w * rs * g2.w + b2.w);
  *(s4v*)(xn + lane * 4)       = w0;
  *(s4v*)(xn + 256 + lane * 4) = w1;
  *(s4v*)(xn + 512 + lane * 4) = w2;
}

// ---------------------------------------------------------------------------
// Double-buffered MFMA GEMM (round-6 schedule). A (rows,K) bf16 rm;
// WT (N,K) bf16 rm. 256 thr, 4 waves; wave computes (BM/4)xBN via IM x JN
// 16x16x32 MFMA per K-step. Stage tile k+1 while computing tile k; ONE
// barrier per step. flags: bit0 GELU, bit1 resid += f32.
// ---------------------------------------------------------------------------
template<int BM, int BN>
__global__ __launch_bounds__(256) void gemm_kernel(
    const bf16* __restrict__ A, const bf16* __restrict__ WT,
    const float* __restrict__ b0, const float* __restrict__ b1,
    const float* __restrict__ b2, int Nsplit,
    bf16* __restrict__ outb, float* __restrict__ resid,
    int M, int N, int K, int flags)
{
  constexpr int IM  = BM / 64;   // MFMA row-subtiles per wave
  constexpr int JN  = BN / 16;   // MFMA col-subtiles per wave
  constexpr int ACH = BM / 64;   // A stage chunks per wave (16 rows each)
  constexpr int BCH = BN / 64;   // B stage chunks per wave
  __shared__ __align__(1024) short As[2][BM * 32];
  __shared__ __align__(1024) short Bs[2][BN * 32];

  int tid = threadIdx.x, wave = tid >> 6, lane = tid & 63;
  int quad = lane >> 4, l16 = lane & 15;
  int m0 = blockIdx.y * BM, n0 = blockIdx.x * BN;
  int wm = wave * (BM / 4);
  int lr = lane >> 2, lc = (lane & 3) * 8;

  const short* Ag = (const short*)A + (long)m0 * K + lc;
  const short* Bg = (const short*)WT + (long)n0 * K + lc;

  const short* ag[ACH]; int alo[ACH];
#pragma unroll
  for (int c = 0; c < ACH; c++) {
    int rbase = wave * (16 * ACH) + c * 16;
    ag[c] = Ag + (long)(rbase + lr) * K;
    alo[c] = rbase * 32;
  }
  const short* bg[BCH]; int blo[BCH];
#pragma unroll
  for (int c = 0; c < BCH; c++) {
    int rbase = wave * (16 * BCH) + c * 16;
    bg[c] = Bg + (long)(rbase + lr) * K;
    blo[c] = rbase * 32;
  }

  f4v zero4 = {0.f, 0.f, 0.f, 0.f};
  f4v acc[IM][JN];
#pragma unroll
  for (int i = 0; i < IM; i++)
#pragma unroll
    for (int j = 0; j < JN; j++) acc[i][j] = zero4;

  int nk = K >> 5;
  // prologue: stage tile 0 -> buf 0
#pragma unroll
  for (int c = 0; c < ACH; c++) async16(ag[c], &As[0][alo[c]]);
#pragma unroll
  for (int c = 0; c < BCH; c++) async16(bg[c], &Bs[0][blo[c]]);
  __syncthreads();   // vmcnt(0) drain: tile 0 ready

  for (int kt = 0; kt < nk; kt++) {
    int cur = kt & 1, nxt = cur ^ 1;
    if (kt + 1 < nk) {
      int ko = (kt + 1) << 5;
#pragma unroll
      for (int c = 0; c < ACH; c++) async16(ag[c] + ko, &As[nxt][alo[c]]);
#pragma unroll
      for (int c = 0; c < BCH; c++) async16(bg[c] + ko, &Bs[nxt][blo[c]]);
    }
    s8v af[IM], bf8[JN];
#pragma unroll
    for (int i = 0; i < IM; i++) {
      const short* p = &As[cur][(wm + i * 16 + l16) * 32 + quad * 8];
      af[i].lo = *(const s4v*)p; af[i].hi = *(const s4v*)(p + 4);
    }
#pragma unroll
    for (int j = 0; j < JN; j++) {
      const short* p = &Bs[cur][(j * 16 + l16) * 32 + quad * 8];
      bf8[j].lo = *(const s4v*)p; bf8[j].hi = *(const s4v*)(p + 4);
    }
#pragma unroll
    for (int i = 0; i < IM; i++)
#pragma unroll
      for (int j = 0; j < JN; j++)
        acc[i][j] = __builtin_amdgcn_mfma_f32_16x16x32_bf16(af[i], bf8[j], acc[i][j], 0, 0, 0);
    __syncthreads();  // all reads of cur done; prefetch of nxt drained
  }

  // epilogue: C/D layout col=lane&15, row=quad*4+reg
#pragma unroll
  for (int i = 0; i < IM; i++) {
    int rbase = m0 + wm + i * 16 + quad * 4;
#pragma unroll
    for (int j = 0; j < JN; j++) {
      int bc = n0 + j * 16;
      int wsel = bc / Nsplit;
      const float* bp = wsel == 0 ? b0 : (wsel == 1 ? b1 : b2);
      float bv = bp[bc - wsel * Nsplit + l16];
      int col = bc + l16;
#pragma unroll
      for (int r = 0; r < 4; r++) {
        int row = rbase + r;
        if (row < M) {
          float v = acc[i][j][r] + bv;
          if (flags & 1) v = 0.5f * v * (1.0f + erff(v * 0.70710678118654752f));
          if (flags & 2) resid[(long)row * N + col] += v;
          else outb[(long)row * N + col] = __float2bfloat16(v);
        }
      }
    }
  }
}

// ---------------------------------------------------------------------------
// Flash-style causal attention, in-register online softmax.
// QKV packed (MPAD,2304). Output Yg bf16. One head-tile (64 q-rows) per
// block; S-row (q-row) is owned by one 16-lane group of one wave, so max/sum
// reduce via 4x __shfl_xor; running m/l live in registers. 3 barriers/tile.
// ---------------------------------------------------------------------------
constexpr int ASTR = 72;

__global__ __launch_bounds__(256) void attn_kernel(
    const bf16* __restrict__ QKV, bf16* __restrict__ Yg)
{
  int qt = blockIdx.x, h = blockIdx.y, b = blockIdx.z;
  int q0 = qt * 64;
  int tid = threadIdx.x, wave = tid >> 6, lane = tid & 63, quad = lane >> 4, l16 = lane & 15;

  __shared__ short Qs[64 * ASTR];
  __shared__ short Ks[64 * ASTR];
  __shared__ short Vt[64 * ASTR];
  __shared__ short Ps[64 * ASTR];

  int r = tid >> 2, c16 = (tid & 3) * 16;
  const short* src = (const short*)QKV;
  s8v zz = {0,0,0,0,0,0,0,0};

  // Q -> LDS
  s8v qv0 = zz, qv1 = zz;
  if (q0 + r < NT) {
    const s8v* p = (const s8v*)(src + (long)(b * NT + q0 + r) * 2304 + h * 64 + c16);
    qv0 = p[0]; qv1 = p[1];
  }
  {
    short* qp = &Qs[r * ASTR + c16];
    *(s4v*)(qp    ) = qv0.lo; *(s4v*)(qp + 4) = qv0.hi;
    *(s4v*)(qp + 8) = qv1.lo; *(s4v*)(qp + 12) = qv1.hi;
  }

  f4v zero4 = {0.f, 0.f, 0.f, 0.f};
  f4v Of[4];
#pragma unroll
  for (int j = 0; j < 4; j++) Of[j] = zero4;
  float m_r[4], l_r[4];
#pragma unroll
  for (int rg = 0; rg < 4; rg++) { m_r[rg] = -1e30f; l_r[rg] = 0.f; }

  int kend = q0 + 63; if (kend > NT - 1) kend = NT - 1;

  // preload K/V tile 0
  s8v kv0 = zz, kv1 = zz, vv0 = zz, vv1 = zz;
  if (r < NT) {
    const s8v* pk = (const s8v*)(src + (long)(b * NT + r) * 2304 + 768 + h * 64 + c16);
    kv0 = pk[0]; kv1 = pk[1];
    const s8v* pvv = (const s8v*)(src + (long)(b * NT + r) * 2304 + 1536 + h * 64 + c16);
    vv0 = pvv[0]; vv1 = pvv[1];
  }

  for (int k0 = 0; k0 <= kend; k0 += 64) {
    __syncthreads();   // prev-tile PV reads done (iter0: also spaces Qs write)
    {
      short* kp = &Ks[r * ASTR + c16];
      *(s4v*)(kp    ) = kv0.lo; *(s4v*)(kp + 4) = kv0.hi;
      *(s4v*)(kp + 8) = kv1.lo; *(s4v*)(kp + 12) = kv1.hi;
      short* vt = &Vt[c16 * ASTR + r];
      vt[ 0 * ASTR] = vv0.s0; vt[ 1 * ASTR] = vv0.s1; vt[ 2 * ASTR] = vv0.s2; vt[ 3 * ASTR] = vv0.s3;
      vt[ 4 * ASTR] = vv0.s4; vt[ 5 * ASTR] = vv0.s5; vt[ 6 * ASTR] = vv0.s6; vt[ 7 * ASTR] = vv0.s7;
      vt[ 8 * ASTR] = vv1.s0; vt[ 9 * ASTR] = vv1.s1; vt[10 * ASTR] = vv1.s2; vt[11 * ASTR] = vv1.s3;
      vt[12 * ASTR] = vv1.s4; vt[13 * ASTR] = vv1.s5; vt[14 * ASTR] = vv1.s6; vt[15 * ASTR] = vv1.s7;
    }
    __syncthreads();   // K/V tile ready

    // prefetch next K/V tile under compute
    int k1 = k0 + 64;
    s8v nk0 = zz, nk1 = zz, nv0 = zz, nv1 = zz;
    if (k1 <= kend && k1 + r < NT) {
      const s8v* pk = (const s8v*)(src + (long)(b * NT + k1 + r) * 2304 + 768 + h * 64 + c16);
      nk0 = pk[0]; nk1 = pk[1];
      const s8v* pvv = (const s8v*)(src + (long)(b * NT + k1 + r) * 2304 + 1536 + h * 64 + c16);
      nv0 = pvv[0]; nv1 = pvv[1];
    }

    // QK^T: sa[j][rg] = S[wave*16+quad*4+rg][j*16+l16]
    f4v sa[4];
#pragma unroll
    for (int j = 0; j < 4; j++) sa[j] = zero4;
#pragma unroll
    for (int ks = 0; ks < 2; ks++) {
      const short* pa = &Qs[(wave * 16 + l16) * ASTR + ks * 32 + quad * 8];
      s8v aq; aq.lo = *(const s4v*)pa; aq.hi = *(const s4v*)(pa + 4);
#pragma unroll
      for (int j = 0; j < 4; j++) {
        const short* pb = &Ks[(j * 16 + l16) * ASTR + ks * 32 + quad * 8];
        s8v bk8; bk8.lo = *(const s4v*)pb; bk8.hi = *(const s4v*)(pb + 4);
        sa[j] = __builtin_amdgcn_mfma_f32_16x16x32_bf16(aq, bk8, sa[j], 0, 0, 0);
      }
    }

    // scale + causal mask in-register
#pragma unroll
    for (int j = 0; j < 4; j++) {
#pragma unroll
      for (int rg = 0; rg < 4; rg++) {
        int gq = q0 + wave * 16 + quad * 4 + rg;
        int gk = k0 + j * 16 + l16;
        sa[j][rg] = (gk <= gq && gq < NT) ? sa[j][rg] * 0.125f : -1e30f;
      }
    }

    // in-register online softmax per row rg (row spread over l16 x j)
#pragma unroll
    for (int rg = 0; rg < 4; rg++) {
      float mx = fmaxf(fmaxf(sa[0][rg], sa[1][rg]), fmaxf(sa[2][rg], sa[3][rg]));
      mx = fmaxf(mx, __shfl_xor(mx, 1));
      mx = fmaxf(mx, __shfl_xor(mx, 2));
      mx = fmaxf(mx, __shfl_xor(mx, 4));
      mx = fmaxf(mx, __shfl_xor(mx, 8));
      float mn = fmaxf(m_r[rg], mx);
      float al = __expf(m_r[rg] - mn);
      m_r[rg] = mn;
      float ps = 0.f;
#pragma unroll
      for (int j = 0; j < 4; j++) {
        float e = __expf(sa[j][rg] - mn);
        sa[j][rg] = e;
        ps += e;
      }
      ps += __shfl_xor(ps, 1);
      ps += __shfl_xor(ps, 2);
      ps += __shfl_xor(ps, 4);
      ps += __shfl_xor(ps, 8);
      l_r[rg] = l_r[rg] * al + ps;
#pragma unroll
      for (int j = 0; j < 4; j++) Of[j][rg] *= al;
    }

    // P -> LDS (bf16) for the PV A-operand
#pragma unroll
    for (int j = 0; j < 4; j++)
#pragma unroll
      for (int rg = 0; rg < 4; rg++)
        Ps[(wave * 16 + quad * 4 + rg) * ASTR + j * 16 + l16] = f2bs(sa[j][rg]);
    __syncthreads();   // Ps ready

    // PV
#pragma unroll
    for (int ks = 0; ks < 2; ks++) {
      const short* pa = &Ps[(wave * 16 + l16) * ASTR + ks * 32 + quad * 8];
      s8v ap8; ap8.lo = *(const s4v*)pa; ap8.hi = *(const s4v*)(pa + 4);
#pragma unroll
      for (int j = 0; j < 4; j++) {
        const short* pb = &Vt[(j * 16 + l16) * ASTR + ks * 32 + quad * 8];
        s8v vp8; vp8.lo = *(const s4v*)pb; vp8.hi = *(const s4v*)(pb + 4);
        Of[j] = __builtin_amdgcn_mfma_f32_16x16x32_bf16(ap8, vp8, Of[j], 0, 0, 0);
      }
    }

    kv0 = nk0; kv1 = nk1; vv0 = nv0; vv1 = nv1;
  }

  // epilogue
#pragma unroll
  for (int rg = 0; rg < 4; rg++) {
    int rloc = wave * 16 + quad * 4 + rg;
    int gq = q0 + rloc;
    if (gq < NT) {
      float inv = 1.0f / l_r[rg];
#pragma unroll
      for (int j = 0; j < 4; j++) {
        float ov = Of[j][rg] * inv;
        Yg[(long)(b * NT + gq) * NC + h * 64 + j * 16 + l16] = __float2bfloat16(ov);
      }
    }
  }
}

// ---------------------------------------------------------------------------
// Merged heads: blocks [0,109) logits; [109,205) action/rtg/intent heads.
// ---------------------------------------------------------------------------
__global__ __launch_bounds__(256) void head_kernel(
    const bf16* __restrict__ XN, const float* __restrict__ Whs,
    const float* __restrict__ bhs,
    const float* __restrict__ Wha, const float* __restrict__ bha,
    const float* __restrict__ Whr, const float* __restrict__ bhr,
    const float* __restrict__ Whi, const float* __restrict__ bhi,
    float* __restrict__ out0, float* __restrict__ outA,
    float* __restrict__ outR, float* __restrict__ outS,
    float* __restrict__ outD)
{
  int tid = threadIdx.x;
  const short* xs = (const short*)XN;
  if (blockIdx.x < 109) {
    int idx = blockIdx.x * 256 + tid;
    if (idx >= NM * 10) return;
    int row = idx / 10, n = idx - row * 10;
    const short* x = xs + (long)row * NC;
    float a0 = bhs[n], a1 = 0.f, a2 = 0.f, a3 = 0.f;
    for (int k = 0; k < NC; k += 4) {
      a0 += bs2f(x[k    ]) * Whs[(k    ) * 10 + n];
      a1 += bs2f(x[k + 1]) * Whs[(k + 1) * 10 + n];
      a2 += bs2f(x[k + 2]) * Whs[(k + 2) * 10 + n];
      a3 += bs2f(x[k + 3]) * Whs[(k + 3) * 10 + n];
    }
    out0[idx] = a0 + a1 + a2 + a3;
    return;
  }
  int blk = blockIdx.x - 109;
  int b = blk / NK, ts = blk - b * NK;
  if (tid >= 93) return;
  if (tid < 40) {
    long row = (long)(b * NT + ts * NTOK + 26) * NC;
    float a0 = bha[tid], a1 = 0.f, a2 = 0.f, a3 = 0.f;
    for (int k = 0; k < NC; k += 4) {
      a0 += bs2f(xs[row + k    ]) * Wha[(k    ) * 40 + tid];
      a1 += bs2f(xs[row + k + 1]) * Wha[(k + 1) * 40 + tid];
      a2 += bs2f(xs[row + k + 2]) * Wha[(k + 2) * 40 + tid];
      a3 += bs2f(xs[row + k + 3]) * Wha[(k + 3) * 40 + tid];
    }
    outA[blk * 40 + tid] = a0 + a1 + a2 + a3;
  } else if (tid == 40) {
    long row = (long)(b * NT + ts * NTOK) * NC;
    float a0 = bhr[0], a1 = 0.f, a2 = 0.f, a3 = 0.f;
    for (int k = 0; k < NC; k += 4) {
      a0 += bs2f(xs[row + k    ]) * Whr[k    ];
      a1 += bs2f(xs[row + k + 1]) * Whr[k + 1];
      a2 += bs2f(xs[row + k + 2]) * Whr[k + 2];
      a3 += bs2f(xs[row + k + 3]) * Whr[k + 3];
    }
    outR[blk] = a0 + a1 + a2 + a3;
  } else {
    int n = tid - 41;
    long row = (long)(b * NT + ts * NTOK + 28) * NC;
    float a0 = bhi[n], a1 = 0.f, a2 = 0.f, a3 = 0.f;
    for (int k = 0; k < NC; k += 4) {
      a0 += bs2f(xs[row + k    ]) * Whi[(k    ) * 52 + n];
      a1 += bs2f(xs[row + k + 1]) * Whi[(k + 1) * 52 + n];
      a2 += bs2f(xs[row + k + 2]) * Whi[(k + 2) * 52 + n];
      a3 += bs2f(xs[row + k + 3]) * Whi[(k + 3) * 52 + n];
    }
    if (n < 26) outS[blk * 26 + n] = a0 + a1 + a2 + a3;
    else        outD[blk * 26 + (n - 26)] = a0 + a1 + a2 + a3;
  }
}

// ---------------------------------------------------------------------------
extern "C" void kernel_launch(void* const* d_in, const int* in_sizes, int n_in,
                              void* d_out, int out_size, void* d_ws, size_t ws_size,
                              hipStream_t stream)
{
  (void)in_sizes; (void)n_in; (void)out_size;

  const int*   states     = (const int*)  d_in[0];
  const int*   actions    = (const int*)  d_in[1];
  const float* rtgs       = (const float*)d_in[2];
  const int*   timesteps  = (const int*)  d_in[3];
  const float* pnp        = (const float*)d_in[4];
  const int*   intentions = (const int*)  d_in[5];
  const float* pos_emb    = (const float*)d_in[6];
  const float* gpe        = (const float*)d_in[7];
  const float* state_tab  = (const float*)d_in[8];
  const float* action_tab = (const float*)d_in[9];
  const float* retW  = (const float*)d_in[10];
  const float* retb  = (const float*)d_in[11];
  const float* pnpW  = (const float*)d_in[12];
  const float* pnpb  = (const float*)d_in[13];
  const float* src_tab = (const float*)d_in[14];
  const float* dst_tab = (const float*)d_in[15];
  const float* intW  = (const float*)d_in[16];
  const float* intb  = (const float*)d_in[17];
  const float* ln1g  = (const float*)d_in[18];
  const float* ln1b  = (const float*)d_in[19];
  const float* ln2g  = (const float*)d_in[20];
  const float* ln2b  = (const float*)d_in[21];
  const float* Wq = (const float*)d_in[22];
  const float* bq = (const float*)d_in[23];
  const float* Wk = (const float*)d_in[24];
  const float* bk = (const float*)d_in[25];
  const float* Wv = (const float*)d_in[26];
  const float* bv = (const float*)d_in[27];
  const float* Wo = (const float*)d_in[28];
  const float* bo = (const float*)d_in[29];
  const float* Wm1 = (const float*)d_in[30];
  const float* bm1 = (const float*)d_in[31];
  const float* Wm2 = (const float*)d_in[32];
  const float* bm2 = (const float*)d_in[33];
  const float* lnfg = (const float*)d_in[34];
  const float* lnfb = (const float*)d_in[35];
  const float* Whs = (const float*)d_in[36];
  const float* bhs = (const float*)d_in[37];
  const float* Wha = (const float*)d_in[38];
  const float* bha = (const float*)d_in[39];
  const float* Whr = (const float*)d_in[40];
  const float* bhr = (const float*)d_in[41];
  const float* Whi = (const float*)d_in[42];
  const float* bhi = (const float*)d_in[43];

  // ws: [0, 30,277,632) activations: X f32 | XN bf16 | QKVb bf16 | Yb bf16
  // then weight region. big path: all-6-layer bf16 weights (84,934,656 B)
  // + int-embed scratch; fallback: single-layer weights (14,155,776 B) with
  // int-embed scratch overlapped (consumed before first layer transpose).
  char* wsb = (char*)d_ws;
  float* X   = (float*)(wsb);
  bf16* XN   = (bf16*)(wsb + 8650752);
  bf16* QKVb = (bf16*)(wsb + 12976128);
  bf16* Yb   = (bf16*)(wsb + 25952256);
  bf16* H1   = QKVb;                          // aliases QKVb|Yb
  bf16* WTbase = (bf16*)(wsb + 30277632);

  const size_t NEED_BIG = 30277632UL + 84934656UL + 2949120UL;  // 118,161,408
  bool big = ws_size >= NEED_BIG;

  long sQKV = 2304L * 768, sO = 768L * 768, sM1 = 3072L * 768, sM2 = 768L * 3072;
  bf16 *WqkvT, *WoT, *Wm1T, *Wm2T, *intWT;
  if (big) {
    WqkvT = WTbase;                 // 6 x sQKV
    WoT   = WqkvT + 6 * sQKV;       // 6 x sO
    Wm1T  = WoT   + 6 * sO;         // 6 x sM1
    Wm2T  = Wm1T  + 6 * sM1;        // 6 x sM2
    intWT = Wm2T  + 6 * sM2;
  } else {
    WqkvT = WTbase;
    WoT   = WqkvT + sQKV;
    Wm1T  = WoT + sO;
    Wm2T  = Wm1T + sM1;
    intWT = WTbase;                 // overlapped; consumed pre-transpose
  }
  bf16* ie_in = intWT + 768L * 1536;   // (128,1536)
  bf16* ieb   = ie_in + 128L * 1536;   // (128,768)

  float* out0 = (float*)d_out;
  float* out1 = out0 + 27840;
  float* out2 = out1 + 3840;
  float* out3 = out2 + 96;
  float* out4 = out3 + 2496;

  // --- embeddings ---
  transpose_kernel<<<dim3(24, 48), 256, 0, stream>>>(intW, intWT, 1536, 768);
  gather_ie_kernel<<<(96 * 1536 + 255) / 256, 256, 0, stream>>>(intentions, src_tab, dst_tab, ie_in);
  gemm_kernel<64, 64><<<dim3(12, 2), 256, 0, stream>>>(ie_in, intWT, intb, intb, intb, 768,
      ieb, nullptr, 96, 768, 1536, 0);
  embed_kernel<<<dim3(96, 3), 256, 0, stream>>>(
      states, actions, rtgs, timesteps, pnp, pos_emb, gpe, state_tab, action_tab,
      retW, retb, pnpW, pnpb, ieb, X);

  if (big)
    transpose_layer_kernel<<<864 * NL, 256, 0, stream>>>(
        Wq, Wk, Wv, Wo, Wm1, Wm2, WqkvT, WoT, Wm1T, Wm2T, 1);

  // --- transformer stack ---
  for (int l = 0; l < NL; l++) {
    const long wofs = (long)l * NC * NC;
    const long mofs = (long)l * NC * 4 * NC;
    if (!big)
      transpose_layer_kernel<<<864, 256, 0, stream>>>(
          Wq + wofs, Wk + wofs, Wv + wofs, Wo + wofs, Wm1 + mofs, Wm2 + mofs,
          WqkvT, WoT, Wm1T, Wm2T, 0);
    bf16* wqkv = big ? WqkvT + l * sQKV : WqkvT;
    bf16* wo   = big ? WoT   + l * sO   : WoT;
    bf16* wm1  = big ? Wm1T  + l * sM1  : Wm1T;
    bf16* wm2  = big ? Wm2T  + l * sM2  : Wm2T;

    ln_kernel<<<NM / 4, 256, 0, stream>>>(X, XN, ln1g + l * NC, ln1b + l * NC);
    gemm_kernel<128, 64><<<dim3(36, 22), 256, 0, stream>>>(XN, wqkv,
        bq + l * NC, bk + l * NC, bv + l * NC, 768, QKVb, nullptr, NM, 2304, NC, 0);
    attn_kernel<<<dim3(22, NH, NBATCH), 256, 0, stream>>>(QKVb, Yb);
    gemm_kernel<64, 64><<<dim3(12, 44), 256, 0, stream>>>(Yb, wo,
        bo + l * NC, bo + l * NC, bo + l * NC, 768, nullptr, X, NM, 768, NC, 2);
    ln_kernel<<<NM / 4, 256, 0, stream>>>(X, XN, ln2g + l * NC, ln2b + l * NC);
    gemm_kernel<128, 64><<<dim3(48, 22), 256, 0, stream>>>(XN, wm1,
        bm1 + l * 4 * NC, bm1 + l * 4 * NC, bm1 + l * 4 * NC, 4 * NC, H1, nullptr,
        NM, 3072, NC, 1);
    gemm_kernel<64, 64><<<dim3(12, 44), 256, 0, stream>>>(H1, wm2,
        bm2 + l * NC, bm2 + l * NC, bm2 + l * NC, 768, nullptr, X, NM, 768, 4 * NC, 2);
  }
  ln_kernel<<<NM / 4, 256, 0, stream>>>(X, XN, lnfg, lnfb);
  head_kernel<<<109 + NBATCH * NK, 256, 0, stream>>>(XN, Whs, bhs, Wha, bha,
      Whr, bhr, Whi, bhi, out0, out1, out2, out3, out4);
}

// Round 5
// 1556.822 us; speedup vs baseline: 1.1050x; 1.0207x over previous
//
#include <hip/hip_runtime.h>
#include <hip/hip_bf16.h>
#include <math.h>

// ---------------------------------------------------------------------------
// GPT decision-transformer forward on gfx950 — round 9.
// Round-9 changes (GEMM geometry, theory: LDS-read-issue bound):
// (1) gemm_kernel gains wave-grid template params <BM,BN,WM,WN,KSPLIT>.
//     QKV/FC1 use <128,128,2,2>: wave owns 64x64 -> 16 MFMA per 8
//     ds_read_b128 (density 2.0 vs 1.33) at ~130 VGPR.
// (2) FC2 uses split-K x2 (<64,64,4,1,2>, grid z=2, 96->48 K-steps,
//     f32 atomicAdd into resid, bias from split 0 only).
// Rest identical to round-8 (best: 1589 us).
// ---------------------------------------------------------------------------

typedef __hip_bfloat16 bf16;
typedef __attribute__((ext_vector_type(4))) short s4v;
typedef __attribute__((ext_vector_type(8))) short s8v;
typedef __attribute__((ext_vector_type(4))) float f4v;
typedef unsigned int u32;

#define DEV static __device__ __forceinline__

constexpr int NBATCH = 2;
constexpr int NK   = 48;
constexpr int NNP  = 25;
constexpr int NC   = 768;
constexpr int NH   = 12;
constexpr int NL   = 6;
constexpr int NTOK = 29;
constexpr int NT   = NK * NTOK;    // 1392
constexpr int NM   = NBATCH * NT;  // 2784
constexpr int MPAD = 2816;         // 22 * 128

DEV float bs2f(short s) {
  unsigned u = ((unsigned)(unsigned short)s) << 16;
  float f; __builtin_memcpy(&f, &u, 4); return f;
}
DEV short f2bs(float f) {
  bf16 h = __float2bfloat16(f);
  short s; __builtin_memcpy(&s, &h, 2); return s;
}

// async global->LDS, 16 B/lane; LDS dest = wave-uniform base + lane*16
DEV void async16(const short* g, short* l) {
  __builtin_amdgcn_global_load_lds(
      (const __attribute__((address_space(1))) u32*)g,
      (__attribute__((address_space(3))) u32*)l, 16, 0, 0);
}

// ---------------------------------------------------------------------------
// Generic f32 (R,C) -> bf16 (C,R) transpose (for intW).
// ---------------------------------------------------------------------------
__global__ __launch_bounds__(256) void transpose_kernel(
    const float* __restrict__ src, bf16* __restrict__ dst, int R, int C)
{
  int c0 = blockIdx.x * 32, r0 = blockIdx.y * 32;
  __shared__ float tl[32][33];
  int rr = threadIdx.x >> 5, cc = threadIdx.x & 31;
#pragma unroll
  for (int p = 0; p < 4; p++)
    tl[rr + p * 8][cc] = src[(long)(r0 + rr + p * 8) * C + c0 + cc];
  __syncthreads();
#pragma unroll
  for (int p = 0; p < 4; p++)
    dst[(long)(c0 + rr + p * 8) * R + r0 + cc] = __float2bfloat16(tl[cc][rr + p * 8]);
}

// Per-layer (or all-layer) weight transpose+convert, 128x64 tiles.
// grid = 864 * nlayers. multi=1: dst gets per-layer offset.
__global__ __launch_bounds__(256) void transpose_layer_kernel(
    const float* __restrict__ Wq, const float* __restrict__ Wk,
    const float* __restrict__ Wv, const float* __restrict__ Wo,
    const float* __restrict__ Wm1, const float* __restrict__ Wm2,
    bf16* __restrict__ WqkvT, bf16* __restrict__ WoT,
    bf16* __restrict__ Wm1T, bf16* __restrict__ Wm2T, int multi)
{
  int blk = blockIdx.x;
  int l = blk / 864, t = blk - l * 864;
  long so = (long)l * 768 * 768;
  long mo = (long)l * 768 * 3072;
  long dl = multi ? l : 0;
  const float* src; bf16* dst; int R, C, tile;
  if (t < 216) {
    int m = t / 72; tile = t - m * 72;
    src = (m == 0 ? Wq : (m == 1 ? Wk : Wv)) + so;
    dst = WqkvT + dl * (2304L * 768) + (long)m * 768 * 768; R = 768; C = 768;
  } else if (t < 288)  { src = Wo + so;  dst = WoT  + dl * (768L * 768);  tile = t - 216; R = 768;  C = 768;  }
  else if (t < 576)    { src = Wm1 + mo; dst = Wm1T + dl * (3072L * 768); tile = t - 288; R = 768;  C = 3072; }
  else                 { src = Wm2 + mo; dst = Wm2T + dl * (768L * 3072); tile = t - 576; R = 3072; C = 768;  }
  int ct = C / 64;
  int tr = tile / ct, tc = tile - tr * ct;
  int r0 = tr * 128, c0 = tc * 64;

  __shared__ short tl[128][66];
  int cg = threadIdx.x & 15, rg = threadIdx.x >> 4;   // 16 col-chunks x 16 row-groups
#pragma unroll
  for (int p = 0; p < 8; p++) {
    int row = rg + p * 16;
    f4v v = *(const f4v*)(src + (long)(r0 + row) * C + c0 + cg * 4);
    tl[row][cg * 4 + 0] = f2bs(v.x);
    tl[row][cg * 4 + 1] = f2bs(v.y);
    tl[row][cg * 4 + 2] = f2bs(v.z);
    tl[row][cg * 4 + 3] = f2bs(v.w);
  }
  __syncthreads();
#pragma unroll
  for (int p = 0; p < 4; p++) {
    int d = rg + p * 16;          // dst row = src col (0..63)
    const short* base = &tl[cg * 8][d];
    s8v w;
    w.s0 = base[0 * 66]; w.s1 = base[1 * 66]; w.s2 = base[2 * 66]; w.s3 = base[3 * 66];
    w.s4 = base[4 * 66]; w.s5 = base[5 * 66]; w.s6 = base[6 * 66]; w.s7 = base[7 * 66];
    *(s8v*)((short*)dst + (long)(c0 + d) * R + r0 + cg * 8) = w;
  }
}

// ---------------------------------------------------------------------------
// gather ie_in (96,1536) bf16 = [src_tab[i0] | dst_tab[i1]]
// ---------------------------------------------------------------------------
__global__ __launch_bounds__(256) void gather_ie_kernel(
    const int* __restrict__ intentions, const float* __restrict__ src_tab,
    const float* __restrict__ dst_tab, bf16* __restrict__ ie_in)
{
  int idx = blockIdx.x * 256 + threadIdx.x;
  if (idx >= 96 * 1536) return;
  int row = idx / 1536, col = idx - row * 1536;
  float v;
  if (col < 768) v = src_tab[intentions[row * 2 + 0] * 768 + col];
  else           v = dst_tab[intentions[row * 2 + 1] * 768 + col - 768];
  ie_in[idx] = __float2bfloat16(v);
}

// ---------------------------------------------------------------------------
// Embedding: X (B*T, C) f32. grid (96, 3); thread owns one channel c.
// ---------------------------------------------------------------------------
__global__ __launch_bounds__(256) void embed_kernel(
    const int* __restrict__ states, const int* __restrict__ actions,
    const float* __restrict__ rtgs, const int* __restrict__ timesteps,
    const float* __restrict__ pnp,
    const float* __restrict__ pos_emb, const float* __restrict__ gpe,
    const float* __restrict__ state_tab, const float* __restrict__ action_tab,
    const float* __restrict__ retW, const float* __restrict__ retb,
    const float* __restrict__ pnpW, const float* __restrict__ pnpb,
    const bf16* __restrict__ ieb, float* __restrict__ X)
{
  int bk = blockIdx.x;
  int b = bk / NK, ts = bk - b * NK;
  int c = blockIdx.y * 256 + threadIdx.x;

  float rtg = rtgs[bk];
  int tstep = timesteps[bk];
  int act   = actions[bk];

  long base = (long)(b * NT + ts * NTOK) * NC;
  float pos = gpe[(long)tstep * NC + c] + pos_emb[ts * NC + c];

  X[base + c] = rtg * retW[c] + retb[c] + pos;
  const int* sp = states + bk * NNP;
#pragma unroll
  for (int i = 0; i < NNP; i++)
    X[base + (1 + i) * NC + c] = state_tab[sp[i] * NC + c] + pos;
  X[base + 26 * NC + c] = action_tab[act * NC + c] + pos;
  float ap = pnpb[c];
  const float* pv = pnp + bk * NNP;
#pragma unroll
  for (int i = 0; i < NNP; i++) ap += pv[i] * pnpW[i * NC + c];
  X[base + 27 * NC + c] = ap + pos;
  X[base + 28 * NC + c] = __bfloat162float(ieb[bk * NC + c]) + pos;
}

// ---------------------------------------------------------------------------
// LayerNorm: X (f32) -> XN (bf16). Wave per row, 4 rows per block.
// ---------------------------------------------------------------------------
__global__ __launch_bounds__(256) void ln_kernel(
    const float* __restrict__ X, bf16* __restrict__ XN,
    const float* __restrict__ g, const float* __restrict__ bt)
{
  int row = blockIdx.x * 4 + (threadIdx.x >> 6);
  int lane = threadIdx.x & 63;
  const float* x = X + (long)row * NC;
  f4v v0 = *(const f4v*)(x + lane * 4);
  f4v v1 = *(const f4v*)(x + 256 + lane * 4);
  f4v v2 = *(const f4v*)(x + 512 + lane * 4);
  float s = v0.x + v0.y + v0.z + v0.w + v1.x + v1.y + v1.z + v1.w
          + v2.x + v2.y + v2.z + v2.w;
#pragma unroll
  for (int o = 32; o > 0; o >>= 1) s += __shfl_xor(s, o);
  float mean = s * (1.0f / NC);
  f4v d0, d1, d2;
  d0.x = v0.x - mean; d0.y = v0.y - mean; d0.z = v0.z - mean; d0.w = v0.w - mean;
  d1.x = v1.x - mean; d1.y = v1.y - mean; d1.z = v1.z - mean; d1.w = v1.w - mean;
  d2.x = v2.x - mean; d2.y = v2.y - mean; d2.z = v2.z - mean; d2.w = v2.w - mean;
  float qq = d0.x*d0.x + d0.y*d0.y + d0.z*d0.z + d0.w*d0.w
           + d1.x*d1.x + d1.y*d1.y + d1.z*d1.z + d1.w*d1.w
           + d2.x*d2.x + d2.y*d2.y + d2.z*d2.z + d2.w*d2.w;
#pragma unroll
  for (int o = 32; o > 0; o >>= 1) qq += __shfl_xor(qq, o);
  float var = qq * (1.0f / NC);
  float rs = 1.0f / sqrtf(var + 1e-5f);
  short* xn = (short*)XN + (long)row * NC;
  f4v g0 = *(const f4v*)(g + lane * 4);
  f4v g1 = *(const f4v*)(g + 256 + lane * 4);
  f4v g2 = *(const f4v*)(g + 512 + lane * 4);
  f4v b0 = *(const f4v*)(bt + lane * 4);
  f4v b1 = *(const f4v*)(bt + 256 + lane * 4);
  f4v b2 = *(const f4v*)(bt + 512 + lane * 4);
  s4v w0, w1, w2;
  w0.x = f2bs(d0.x * rs * g0.x + b0.x); w0.y = f2bs(d0.y * rs * g0.y + b0.y);
  w0.z = f2bs(d0.z * rs * g0.z + b0.z); w0.w = f2bs(d0.w * rs * g0.w + b0.w);
  w1.x = f2bs(d1.x * rs * g1.x + b1.x); w1.y = f2bs(d1.y * rs * g1.y + b1.y);
  w1.z = f2bs(d1.z * rs * g1.z + b1.z); w1.w = f2bs(d1.w * rs * g1.w + b1.w);
  w2.x = f2bs(d2.x * rs * g2.x + b2.x); w2.y = f2bs(d2.y * rs * g2.y + b2.y);
  w2.z = f2bs(d2.z * rs * g2.z + b2.z); w2.w = f2bs(d2.w * rs * g2.w + b2.w);
  *(s4v*)(xn + lane * 4)       = w0;
  *(s4v*)(xn + 256 + lane * 4) = w1;
  *(s4v*)(xn + 512 + lane * 4) = w2;
}

// ---------------------------------------------------------------------------
// Double-buffered MFMA GEMM. A (rows,K) bf16 rm; WT (N,K) bf16 rm.
// Wave grid WM x WN (WM*WN = 4); wave computes IM*16 x JN*16.
// KSPLIT>1: blockIdx.z selects K-range; resid path uses atomicAdd and only
// split 0 adds bias. flags: bit0 GELU, bit1 resid += f32.
// ---------------------------------------------------------------------------
template<int BM, int BN, int WM, int WN, int KSPLIT = 1>
__global__ __launch_bounds__(256) void gemm_kernel(
    const bf16* __restrict__ A, const bf16* __restrict__ WT,
    const float* __restrict__ b0, const float* __restrict__ b1,
    const float* __restrict__ b2, int Nsplit,
    bf16* __restrict__ outb, float* __restrict__ resid,
    int M, int N, int K, int flags)
{
  constexpr int IM  = BM / (WM * 16);  // MFMA row-subtiles per wave
  constexpr int JN  = BN / (WN * 16);  // MFMA col-subtiles per wave
  constexpr int ACH = BM / 64;         // A stage chunks (16 rows each/wave)
  constexpr int BCH = BN / 64;         // B stage chunks
  __shared__ __align__(1024) short As[2][BM * 32];
  __shared__ __align__(1024) short Bs[2][BN * 32];

  int tid = threadIdx.x, wave = tid >> 6, lane = tid & 63;
  int quad = lane >> 4, l16 = lane & 15;
  int m0 = blockIdx.y * BM, n0 = blockIdx.x * BN;
  int wm = (wave / WN) * (IM * 16);
  int wn = (wave % WN) * (JN * 16);
  int lr = lane >> 2, lc = (lane & 3) * 8;

  int kbeg = (KSPLIT > 1) ? blockIdx.z * (K / KSPLIT) : 0;
  int kl = K / KSPLIT;

  const short* Ag = (const short*)A + (long)m0 * K + kbeg + lc;
  const short* Bg = (const short*)WT + (long)n0 * K + kbeg + lc;

  const short* ag[ACH]; int alo[ACH];
#pragma unroll
  for (int c = 0; c < ACH; c++) {
    int rbase = wave * (16 * ACH) + c * 16;
    ag[c] = Ag + (long)(rbase + lr) * K;
    alo[c] = rbase * 32;
  }
  const short* bg[BCH]; int blo[BCH];
#pragma unroll
  for (int c = 0; c < BCH; c++) {
    int rbase = wave * (16 * BCH) + c * 16;
    bg[c] = Bg + (long)(rbase + lr) * K;
    blo[c] = rbase * 32;
  }

  f4v zero4 = {0.f, 0.f, 0.f, 0.f};
  f4v acc[IM][JN];
#pragma unroll
  for (int i = 0; i < IM; i++)
#pragma unroll
    for (int j = 0; j < JN; j++) acc[i][j] = zero4;

  int nk = kl >> 5;
  // prologue: stage tile 0 -> buf 0
#pragma unroll
  for (int c = 0; c < ACH; c++) async16(ag[c], &As[0][alo[c]]);
#pragma unroll
  for (int c = 0; c < BCH; c++) async16(bg[c], &Bs[0][blo[c]]);
  __syncthreads();   // vmcnt(0) drain: tile 0 ready

  for (int kt = 0; kt < nk; kt++) {
    int cur = kt & 1, nxt = cur ^ 1;
    if (kt + 1 < nk) {
      int ko = (kt + 1) << 5;
#pragma unroll
      for (int c = 0; c < ACH; c++) async16(ag[c] + ko, &As[nxt][alo[c]]);
#pragma unroll
      for (int c = 0; c < BCH; c++) async16(bg[c] + ko, &Bs[nxt][blo[c]]);
    }
    s8v af[IM], bf8[JN];
#pragma unroll
    for (int i = 0; i < IM; i++) {
      const short* p = &As[cur][(wm + i * 16 + l16) * 32 + quad * 8];
      af[i].lo = *(const s4v*)p; af[i].hi = *(const s4v*)(p + 4);
    }
#pragma unroll
    for (int j = 0; j < JN; j++) {
      const short* p = &Bs[cur][(wn + j * 16 + l16) * 32 + quad * 8];
      bf8[j].lo = *(const s4v*)p; bf8[j].hi = *(const s4v*)(p + 4);
    }
#pragma unroll
    for (int i = 0; i < IM; i++)
#pragma unroll
      for (int j = 0; j < JN; j++)
        acc[i][j] = __builtin_amdgcn_mfma_f32_16x16x32_bf16(af[i], bf8[j], acc[i][j], 0, 0, 0);
    __syncthreads();  // all reads of cur done; prefetch of nxt drained
  }

  // epilogue: C/D layout col=lane&15, row=quad*4+reg
  bool addb = (KSPLIT == 1) || (blockIdx.z == 0);
#pragma unroll
  for (int i = 0; i < IM; i++) {
    int rbase = m0 + wm + i * 16 + quad * 4;
#pragma unroll
    for (int j = 0; j < JN; j++) {
      int bc = n0 + wn + j * 16;
      int wsel = bc / Nsplit;
      const float* bp = wsel == 0 ? b0 : (wsel == 1 ? b1 : b2);
      float bv = addb ? bp[bc - wsel * Nsplit + l16] : 0.f;
      int col = bc + l16;
#pragma unroll
      for (int r = 0; r < 4; r++) {
        int row = rbase + r;
        if (row < M) {
          float v = acc[i][j][r] + bv;
          if (flags & 1) v = 0.5f * v * (1.0f + erff(v * 0.70710678118654752f));
          if (flags & 2) {
            if (KSPLIT > 1) atomicAdd(&resid[(long)row * N + col], v);
            else            resid[(long)row * N + col] += v;
          } else outb[(long)row * N + col] = __float2bfloat16(v);
        }
      }
    }
  }
}

// ---------------------------------------------------------------------------
// Flash-style causal attention, in-register online softmax.
// ---------------------------------------------------------------------------
constexpr int ASTR = 72;

__global__ __launch_bounds__(256) void attn_kernel(
    const bf16* __restrict__ QKV, bf16* __restrict__ Yg)
{
  int qt = blockIdx.x, h = blockIdx.y, b = blockIdx.z;
  int q0 = qt * 64;
  int tid = threadIdx.x, wave = tid >> 6, lane = tid & 63, quad = lane >> 4, l16 = lane & 15;

  __shared__ short Qs[64 * ASTR];
  __shared__ short Ks[64 * ASTR];
  __shared__ short Vt[64 * ASTR];
  __shared__ short Ps[64 * ASTR];

  int r = tid >> 2, c16 = (tid & 3) * 16;
  const short* src = (const short*)QKV;
  s8v zz = {0,0,0,0,0,0,0,0};

  // Q -> LDS
  s8v qv0 = zz, qv1 = zz;
  if (q0 + r < NT) {
    const s8v* p = (const s8v*)(src + (long)(b * NT + q0 + r) * 2304 + h * 64 + c16);
    qv0 = p[0]; qv1 = p[1];
  }
  {
    short* qp = &Qs[r * ASTR + c16];
    *(s4v*)(qp    ) = qv0.lo; *(s4v*)(qp + 4) = qv0.hi;
    *(s4v*)(qp + 8) = qv1.lo; *(s4v*)(qp + 12) = qv1.hi;
  }

  f4v zero4 = {0.f, 0.f, 0.f, 0.f};
  f4v Of[4];
#pragma unroll
  for (int j = 0; j < 4; j++) Of[j] = zero4;
  float m_r[4], l_r[4];
#pragma unroll
  for (int rg = 0; rg < 4; rg++) { m_r[rg] = -1e30f; l_r[rg] = 0.f; }

  int kend = q0 + 63; if (kend > NT - 1) kend = NT - 1;

  // preload K/V tile 0
  s8v kv0 = zz, kv1 = zz, vv0 = zz, vv1 = zz;
  if (r < NT) {
    const s8v* pk = (const s8v*)(src + (long)(b * NT + r) * 2304 + 768 + h * 64 + c16);
    kv0 = pk[0]; kv1 = pk[1];
    const s8v* pvv = (const s8v*)(src + (long)(b * NT + r) * 2304 + 1536 + h * 64 + c16);
    vv0 = pvv[0]; vv1 = pvv[1];
  }

  for (int k0 = 0; k0 <= kend; k0 += 64) {
    __syncthreads();
    {
      short* kp = &Ks[r * ASTR + c16];
      *(s4v*)(kp    ) = kv0.lo; *(s4v*)(kp + 4) = kv0.hi;
      *(s4v*)(kp + 8) = kv1.lo; *(s4v*)(kp + 12) = kv1.hi;
      short* vt = &Vt[c16 * ASTR + r];
      vt[ 0 * ASTR] = vv0.s0; vt[ 1 * ASTR] = vv0.s1; vt[ 2 * ASTR] = vv0.s2; vt[ 3 * ASTR] = vv0.s3;
      vt[ 4 * ASTR] = vv0.s4; vt[ 5 * ASTR] = vv0.s5; vt[ 6 * ASTR] = vv0.s6; vt[ 7 * ASTR] = vv0.s7;
      vt[ 8 * ASTR] = vv1.s0; vt[ 9 * ASTR] = vv1.s1; vt[10 * ASTR] = vv1.s2; vt[11 * ASTR] = vv1.s3;
      vt[12 * ASTR] = vv1.s4; vt[13 * ASTR] = vv1.s5; vt[14 * ASTR] = vv1.s6; vt[15 * ASTR] = vv1.s7;
    }
    __syncthreads();

    int k1 = k0 + 64;
    s8v nk0 = zz, nk1 = zz, nv0 = zz, nv1 = zz;
    if (k1 <= kend && k1 + r < NT) {
      const s8v* pk = (const s8v*)(src + (long)(b * NT + k1 + r) * 2304 + 768 + h * 64 + c16);
      nk0 = pk[0]; nk1 = pk[1];
      const s8v* pvv = (const s8v*)(src + (long)(b * NT + k1 + r) * 2304 + 1536 + h * 64 + c16);
      nv0 = pvv[0]; nv1 = pvv[1];
    }

    f4v sa[4];
#pragma unroll
    for (int j = 0; j < 4; j++) sa[j] = zero4;
#pragma unroll
    for (int ks = 0; ks < 2; ks++) {
      const short* pa = &Qs[(wave * 16 + l16) * ASTR + ks * 32 + quad * 8];
      s8v aq; aq.lo = *(const s4v*)pa; aq.hi = *(const s4v*)(pa + 4);
#pragma unroll
      for (int j = 0; j < 4; j++) {
        const short* pb = &Ks[(j * 16 + l16) * ASTR + ks * 32 + quad * 8];
        s8v bk8; bk8.lo = *(const s4v*)pb; bk8.hi = *(const s4v*)(pb + 4);
        sa[j] = __builtin_amdgcn_mfma_f32_16x16x32_bf16(aq, bk8, sa[j], 0, 0, 0);
      }
    }

#pragma unroll
    for (int j = 0; j < 4; j++) {
#pragma unroll
      for (int rg = 0; rg < 4; rg++) {
        int gq = q0 + wave * 16 + quad * 4 + rg;
        int gk = k0 + j * 16 + l16;
        sa[j][rg] = (gk <= gq && gq < NT) ? sa[j][rg] * 0.125f : -1e30f;
      }
    }

#pragma unroll
    for (int rg = 0; rg < 4; rg++) {
      float mx = fmaxf(fmaxf(sa[0][rg], sa[1][rg]), fmaxf(sa[2][rg], sa[3][rg]));
      mx = fmaxf(mx, __shfl_xor(mx, 1));
      mx = fmaxf(mx, __shfl_xor(mx, 2));
      mx = fmaxf(mx, __shfl_xor(mx, 4));
      mx = fmaxf(mx, __shfl_xor(mx, 8));
      float mn = fmaxf(m_r[rg], mx);
      float al = __expf(m_r[rg] - mn);
      m_r[rg] = mn;
      float ps = 0.f;
#pragma unroll
      for (int j = 0; j < 4; j++) {
        float e = __expf(sa[j][rg] - mn);
        sa[j][rg] = e;
        ps += e;
      }
      ps += __shfl_xor(ps, 1);
      ps += __shfl_xor(ps, 2);
      ps += __shfl_xor(ps, 4);
      ps += __shfl_xor(ps, 8);
      l_r[rg] = l_r[rg] * al + ps;
#pragma unroll
      for (int j = 0; j < 4; j++) Of[j][rg] *= al;
    }

#pragma unroll
    for (int j = 0; j < 4; j++)
#pragma unroll
      for (int rg = 0; rg < 4; rg++)
        Ps[(wave * 16 + quad * 4 + rg) * ASTR + j * 16 + l16] = f2bs(sa[j][rg]);
    __syncthreads();

#pragma unroll
    for (int ks = 0; ks < 2; ks++) {
      const short* pa = &Ps[(wave * 16 + l16) * ASTR + ks * 32 + quad * 8];
      s8v ap8; ap8.lo = *(const s4v*)pa; ap8.hi = *(const s4v*)(pa + 4);
#pragma unroll
      for (int j = 0; j < 4; j++) {
        const short* pb = &Vt[(j * 16 + l16) * ASTR + ks * 32 + quad * 8];
        s8v vp8; vp8.lo = *(const s4v*)pb; vp8.hi = *(const s4v*)(pb + 4);
        Of[j] = __builtin_amdgcn_mfma_f32_16x16x32_bf16(ap8, vp8, Of[j], 0, 0, 0);
      }
    }

    kv0 = nk0; kv1 = nk1; vv0 = nv0; vv1 = nv1;
  }

#pragma unroll
  for (int rg = 0; rg < 4; rg++) {
    int rloc = wave * 16 + quad * 4 + rg;
    int gq = q0 + rloc;
    if (gq < NT) {
      float inv = 1.0f / l_r[rg];
#pragma unroll
      for (int j = 0; j < 4; j++) {
        float ov = Of[j][rg] * inv;
        Yg[(long)(b * NT + gq) * NC + h * 64 + j * 16 + l16] = __float2bfloat16(ov);
      }
    }
  }
}

// ---------------------------------------------------------------------------
// Merged heads: blocks [0,109) logits; [109,205) action/rtg/intent heads.
// ---------------------------------------------------------------------------
__global__ __launch_bounds__(256) void head_kernel(
    const bf16* __restrict__ XN, const float* __restrict__ Whs,
    const float* __restrict__ bhs,
    const float* __restrict__ Wha, const float* __restrict__ bha,
    const float* __restrict__ Whr, const float* __restrict__ bhr,
    const float* __restrict__ Whi, const float* __restrict__ bhi,
    float* __restrict__ out0, float* __restrict__ outA,
    float* __restrict__ outR, float* __restrict__ outS,
    float* __restrict__ outD)
{
  int tid = threadIdx.x;
  const short* xs = (const short*)XN;
  if (blockIdx.x < 109) {
    int idx = blockIdx.x * 256 + tid;
    if (idx >= NM * 10) return;
    int row = idx / 10, n = idx - row * 10;
    const short* x = xs + (long)row * NC;
    float a0 = bhs[n], a1 = 0.f, a2 = 0.f, a3 = 0.f;
    for (int k = 0; k < NC; k += 4) {
      a0 += bs2f(x[k    ]) * Whs[(k    ) * 10 + n];
      a1 += bs2f(x[k + 1]) * Whs[(k + 1) * 10 + n];
      a2 += bs2f(x[k + 2]) * Whs[(k + 2) * 10 + n];
      a3 += bs2f(x[k + 3]) * Whs[(k + 3) * 10 + n];
    }
    out0[idx] = a0 + a1 + a2 + a3;
    return;
  }
  int blk = blockIdx.x - 109;
  int b = blk / NK, ts = blk - b * NK;
  if (tid >= 93) return;
  if (tid < 40) {
    long row = (long)(b * NT + ts * NTOK + 26) * NC;
    float a0 = bha[tid], a1 = 0.f, a2 = 0.f, a3 = 0.f;
    for (int k = 0; k < NC; k += 4) {
      a0 += bs2f(xs[row + k    ]) * Wha[(k    ) * 40 + tid];
      a1 += bs2f(xs[row + k + 1]) * Wha[(k + 1) * 40 + tid];
      a2 += bs2f(xs[row + k + 2]) * Wha[(k + 2) * 40 + tid];
      a3 += bs2f(xs[row + k + 3]) * Wha[(k + 3) * 40 + tid];
    }
    outA[blk * 40 + tid] = a0 + a1 + a2 + a3;
  } else if (tid == 40) {
    long row = (long)(b * NT + ts * NTOK) * NC;
    float a0 = bhr[0], a1 = 0.f, a2 = 0.f, a3 = 0.f;
    for (int k = 0; k < NC; k += 4) {
      a0 += bs2f(xs[row + k    ]) * Whr[k    ];
      a1 += bs2f(xs[row + k + 1]) * Whr[k + 1];
      a2 += bs2f(xs[row + k + 2]) * Whr[k + 2];
      a3 += bs2f(xs[row + k + 3]) * Whr[k + 3];
    }
    outR[blk] = a0 + a1 + a2 + a3;
  } else {
    int n = tid - 41;
    long row = (long)(b * NT + ts * NTOK + 28) * NC;
    float a0 = bhi[n], a1 = 0.f, a2 = 0.f, a3 = 0.f;
    for (int k = 0; k < NC; k += 4) {
      a0 += bs2f(xs[row + k    ]) * Whi[(k    ) * 52 + n];
      a1 += bs2f(xs[row + k + 1]) * Whi[(k + 1) * 52 + n];
      a2 += bs2f(xs[row + k + 2]) * Whi[(k + 2) * 52 + n];
      a3 += bs2f(xs[row + k + 3]) * Whi[(k + 3) * 52 + n];
    }
    if (n < 26) outS[blk * 26 + n] = a0 + a1 + a2 + a3;
    else        outD[blk * 26 + (n - 26)] = a0 + a1 + a2 + a3;
  }
}

// ---------------------------------------------------------------------------
extern "C" void kernel_launch(void* const* d_in, const int* in_sizes, int n_in,
                              void* d_out, int out_size, void* d_ws, size_t ws_size,
                              hipStream_t stream)
{
  (void)in_sizes; (void)n_in; (void)out_size;

  const int*   states     = (const int*)  d_in[0];
  const int*   actions    = (const int*)  d_in[1];
  const float* rtgs       = (const float*)d_in[2];
  const int*   timesteps  = (const int*)  d_in[3];
  const float* pnp        = (const float*)d_in[4];
  const int*   intentions = (const int*)  d_in[5];
  const float* pos_emb    = (const float*)d_in[6];
  const float* gpe        = (const float*)d_in[7];
  const float* state_tab  = (const float*)d_in[8];
  const float* action_tab = (const float*)d_in[9];
  const float* retW  = (const float*)d_in[10];
  const float* retb  = (const float*)d_in[11];
  const float* pnpW  = (const float*)d_in[12];
  const float* pnpb  = (const float*)d_in[13];
  const float* src_tab = (const float*)d_in[14];
  const float* dst_tab = (const float*)d_in[15];
  const float* intW  = (const float*)d_in[16];
  const float* intb  = (const float*)d_in[17];
  const float* ln1g  = (const float*)d_in[18];
  const float* ln1b  = (const float*)d_in[19];
  const float* ln2g  = (const float*)d_in[20];
  const float* ln2b  = (const float*)d_in[21];
  const float* Wq = (const float*)d_in[22];
  const float* bq = (const float*)d_in[23];
  const float* Wk = (const float*)d_in[24];
  const float* bk = (const float*)d_in[25];
  const float* Wv = (const float*)d_in[26];
  const float* bv = (const float*)d_in[27];
  const float* Wo = (const float*)d_in[28];
  const float* bo = (const float*)d_in[29];
  const float* Wm1 = (const float*)d_in[30];
  const float* bm1 = (const float*)d_in[31];
  const float* Wm2 = (const float*)d_in[32];
  const float* bm2 = (const float*)d_in[33];
  const float* lnfg = (const float*)d_in[34];
  const float* lnfb = (const float*)d_in[35];
  const float* Whs = (const float*)d_in[36];
  const float* bhs = (const float*)d_in[37];
  const float* Wha = (const float*)d_in[38];
  const float* bha = (const float*)d_in[39];
  const float* Whr = (const float*)d_in[40];
  const float* bhr = (const float*)d_in[41];
  const float* Whi = (const float*)d_in[42];
  const float* bhi = (const float*)d_in[43];

  char* wsb = (char*)d_ws;
  float* X   = (float*)(wsb);
  bf16* XN   = (bf16*)(wsb + 8650752);
  bf16* QKVb = (bf16*)(wsb + 12976128);
  bf16* Yb   = (bf16*)(wsb + 25952256);
  bf16* H1   = QKVb;                          // aliases QKVb|Yb
  bf16* WTbase = (bf16*)(wsb + 30277632);

  const size_t NEED_BIG = 30277632UL + 84934656UL + 2949120UL;  // 118,161,408
  bool big = ws_size >= NEED_BIG;

  long sQKV = 2304L * 768, sO = 768L * 768, sM1 = 3072L * 768, sM2 = 768L * 3072;
  bf16 *WqkvT, *WoT, *Wm1T, *Wm2T, *intWT;
  if (big) {
    WqkvT = WTbase;                 // 6 x sQKV
    WoT   = WqkvT + 6 * sQKV;       // 6 x sO
    Wm1T  = WoT   + 6 * sO;         // 6 x sM1
    Wm2T  = Wm1T  + 6 * sM1;        // 6 x sM2
    intWT = Wm2T  + 6 * sM2;
  } else {
    WqkvT = WTbase;
    WoT   = WqkvT + sQKV;
    Wm1T  = WoT + sO;
    Wm2T  = Wm1T + sM1;
    intWT = WTbase;                 // overlapped; consumed pre-transpose
  }
  bf16* ie_in = intWT + 768L * 1536;   // (128,1536)
  bf16* ieb   = ie_in + 128L * 1536;   // (128,768)

  float* out0 = (float*)d_out;
  float* out1 = out0 + 27840;
  float* out2 = out1 + 3840;
  float* out3 = out2 + 96;
  float* out4 = out3 + 2496;

  // --- embeddings ---
  transpose_kernel<<<dim3(24, 48), 256, 0, stream>>>(intW, intWT, 1536, 768);
  gather_ie_kernel<<<(96 * 1536 + 255) / 256, 256, 0, stream>>>(intentions, src_tab, dst_tab, ie_in);
  gemm_kernel<64, 64, 4, 1><<<dim3(12, 2), 256, 0, stream>>>(ie_in, intWT, intb, intb, intb, 768,
      ieb, nullptr, 96, 768, 1536, 0);
  embed_kernel<<<dim3(96, 3), 256, 0, stream>>>(
      states, actions, rtgs, timesteps, pnp, pos_emb, gpe, state_tab, action_tab,
      retW, retb, pnpW, pnpb, ieb, X);

  if (big)
    transpose_layer_kernel<<<864 * NL, 256, 0, stream>>>(
        Wq, Wk, Wv, Wo, Wm1, Wm2, WqkvT, WoT, Wm1T, Wm2T, 1);

  // --- transformer stack ---
  for (int l = 0; l < NL; l++) {
    const long wofs = (long)l * NC * NC;
    const long mofs = (long)l * NC * 4 * NC;
    if (!big)
      transpose_layer_kernel<<<864, 256, 0, stream>>>(
          Wq + wofs, Wk + wofs, Wv + wofs, Wo + wofs, Wm1 + mofs, Wm2 + mofs,
          WqkvT, WoT, Wm1T, Wm2T, 0);
    bf16* wqkv = big ? WqkvT + l * sQKV : WqkvT;
    bf16* wo   = big ? WoT   + l * sO   : WoT;
    bf16* wm1  = big ? Wm1T  + l * sM1  : Wm1T;
    bf16* wm2  = big ? Wm2T  + l * sM2  : Wm2T;

    ln_kernel<<<NM / 4, 256, 0, stream>>>(X, XN, ln1g + l * NC, ln1b + l * NC);
    gemm_kernel<128, 128, 2, 2><<<dim3(18, 22), 256, 0, stream>>>(XN, wqkv,
        bq + l * NC, bk + l * NC, bv + l * NC, 768, QKVb, nullptr, NM, 2304, NC, 0);
    attn_kernel<<<dim3(22, NH, NBATCH), 256, 0, stream>>>(QKVb, Yb);
    gemm_kernel<64, 64, 4, 1><<<dim3(12, 44), 256, 0, stream>>>(Yb, wo,
        bo + l * NC, bo + l * NC, bo + l * NC, 768, nullptr, X, NM, 768, NC, 2);
    ln_kernel<<<NM / 4, 256, 0, stream>>>(X, XN, ln2g + l * NC, ln2b + l * NC);
    gemm_kernel<128, 128, 2, 2><<<dim3(24, 22), 256, 0, stream>>>(XN, wm1,
        bm1 + l * 4 * NC, bm1 + l * 4 * NC, bm1 + l * 4 * NC, 4 * NC, H1, nullptr,
        NM, 3072, NC, 1);
    gemm_kernel<64, 64, 4, 1, 2><<<dim3(12, 44, 2), 256, 0, stream>>>(H1, wm2,
        bm2 + l * NC, bm2 + l * NC, bm2 + l * NC, 768, nullptr, X, NM, 768, 4 * NC, 2);
  }
  ln_kernel<<<NM / 4, 256, 0, stream>>>(X, XN, lnfg, lnfb);
  head_kernel<<<109 + NBATCH * NK, 256, 0, stream>>>(XN, Whs, bhs, Wha, bha,
      Whr, bhr, Whi, bhi, out0, out1, out2, out3, out4);
}